// Round 9
// baseline (182.664 us; speedup 1.0000x reference)
//
#include <hip/hip_runtime.h>
#include <hip/hip_bf16.h>
#include <math.h>

// ---------------------------------------------------------------------------
// CrossCausalAttentionBlock on MI355X (gfx950)
// B=8, T=1024 (V=4 blocks of 256), C=512, NH=8, hd=64
// R9: gemmsk LDS packed 128->64 KB (AS/BS tight, CF overlays) -> 2 blocks/CU
//     for the split-K O and PR GEMMs; prep re-merged into one launch.
// ---------------------------------------------------------------------------

typedef __bf16 bf16;
typedef __bf16 bf16x8 __attribute__((ext_vector_type(8)));
typedef __bf16 bf16x4 __attribute__((ext_vector_type(4)));
typedef float  f32x4  __attribute__((ext_vector_type(4)));

__device__ __forceinline__ void gload_lds16(const void* g, void* l) {
  __builtin_amdgcn_global_load_lds(
      (__attribute__((address_space(1))) void*)(g),
      (__attribute__((address_space(3))) void*)(l), 16, 0, 0);
}

// ---------------------------------------------------------------------------
// Kernel 1: prep = weight converts (blocks 0..3071) + gather+LN1 (3072..4607)
// LN path register-resident with bf16x8/f32x4 vector stores (R8 form).
// ---------------------------------------------------------------------------
__global__ __launch_bounds__(256)
void prep_k(const float* __restrict__ Wq, const float* __restrict__ Wkv,
            const float* __restrict__ Wo, const float* __restrict__ Wfc,
            const float* __restrict__ Wpr,
            bf16* __restrict__ WqT, bf16* __restrict__ WkvT,
            bf16* __restrict__ WoT, bf16* __restrict__ WfcT,
            bf16* __restrict__ WprT,
            const float* __restrict__ xi, const float* __restrict__ xj,
            const float* __restrict__ xc,
            const float* __restrict__ g, const float* __restrict__ bb,
            bf16* __restrict__ qs, bf16* __restrict__ kvs,
            float* __restrict__ cs0)
{
  __shared__ float tt[32][33];
  __shared__ float red[4][32];
  const int t = blockIdx.x;
  const int tid = threadIdx.x;
  if (t < 3072) { // ---- weight transpose-convert, 32x32 tiles
    const float* W; bf16* Wt; int K, N, lognx, tl;
    if (t < 256)       { W = Wq;  Wt = WqT;  K = 512;  N = 512;  lognx = 4; tl = t; }
    else if (t < 768)  { W = Wkv; Wt = WkvT; K = 512;  N = 1024; lognx = 5; tl = t - 256; }
    else if (t < 1024) { W = Wo;  Wt = WoT;  K = 512;  N = 512;  lognx = 4; tl = t - 768; }
    else if (t < 2048) { W = Wfc; Wt = WfcT; K = 512;  N = 2048; lognx = 6; tl = t - 1024; }
    else               { W = Wpr; Wt = WprT; K = 2048; N = 512;  lognx = 4; tl = t - 2048; }
    const int bx = tl & ((1 << lognx) - 1), by = tl >> lognx;
    const int x = tid & 31, y = tid >> 5;
    const int n0 = bx << 5, k0 = by << 5;
#pragma unroll
    for (int yy = y; yy < 32; yy += 8)
      tt[yy][x] = W[(size_t)(k0 + yy) * N + n0 + x];
    __syncthreads();
#pragma unroll
    for (int yy = y; yy < 32; yy += 8)
      Wt[(size_t)(n0 + yy) * K + k0 + x] = (bf16)tt[x][yy];
    return;
  }
  // ---- gather [v,b,c,h,w] -> [b,t,c] + LN1, register-resident
  const int u = t - 3072;
  const int sel = u >> 9, bid = u & 511;
  const int hh = bid & 15, b = (bid >> 4) & 7, v = bid >> 7;
  const float* src = (sel == 0) ? xi : ((sel == 1) ? xj : xc);
  const size_t base = ((size_t)(v * 8 + b) * 512) * 256 + (size_t)hh * 16;
  const int q = tid & 3, chb = tid >> 2;
  const int wid = tid >> 6, lane = tid & 63;
  const int cb = chb << 3; // 8 consecutive channels

  float gr[8], br[8];
  *(f32x4*)&gr[0] = *(const f32x4*)&g[cb];
  *(f32x4*)&gr[4] = *(const f32x4*)&g[cb + 4];
  *(f32x4*)&br[0] = *(const f32x4*)&bb[cb];
  *(f32x4*)&br[4] = *(const f32x4*)&bb[cb + 4];

  f32x4 x[8];
#pragma unroll
  for (int k = 0; k < 8; ++k)
    x[k] = *(const f32x4*)&src[base + (size_t)(cb + k) * 256 + (q << 2)];

  float s[4] = {0.f, 0.f, 0.f, 0.f}, ss[4] = {0.f, 0.f, 0.f, 0.f};
#pragma unroll
  for (int k = 0; k < 8; ++k)
#pragma unroll
    for (int i = 0; i < 4; ++i) {
      s[i] += x[k][i];
      ss[i] += x[k][i] * x[k][i];
    }
#pragma unroll
  for (int off = 4; off < 64; off <<= 1)
#pragma unroll
    for (int i = 0; i < 4; ++i) {
      s[i] += __shfl_xor(s[i], off);
      ss[i] += __shfl_xor(ss[i], off);
    }
  if (lane < 16) {
    red[wid][(lane & 3) * 4 + (lane >> 2)]      = s[lane >> 2];
    red[wid][16 + (lane & 3) * 4 + (lane >> 2)] = ss[lane >> 2];
  }
  __syncthreads();
  float mu[4], rs[4];
#pragma unroll
  for (int i = 0; i < 4; ++i) {
    const int e = q * 4 + i;
    float st  = red[0][e] + red[1][e] + red[2][e] + red[3][e];
    float sst = red[0][16 + e] + red[1][16 + e] + red[2][16 + e] + red[3][16 + e];
    mu[i] = st * (1.f / 512.f);
    rs[i] = rsqrtf(sst * (1.f / 512.f) - mu[i] * mu[i] + 1e-5f);
  }
  const int tkb = v * 256 + hh * 16 + (q << 2);
  bf16* dstb = (sel == 0) ? qs : kvs;
#pragma unroll
  for (int i = 0; i < 4; ++i) {
    const size_t orow = ((size_t)b * 1024 + tkb + i) * 512;
    if (sel == 2) {
      f32x4 o0, o1;
#pragma unroll
      for (int k = 0; k < 4; ++k) {
        o0[k] = (x[k][i] - mu[i]) * rs[i] * gr[k] + br[k];
        o1[k] = (x[k + 4][i] - mu[i]) * rs[i] * gr[k + 4] + br[k + 4];
      }
      *(f32x4*)&cs0[orow + cb]     = o0;
      *(f32x4*)&cs0[orow + cb + 4] = o1;
    } else {
      bf16x8 o;
#pragma unroll
      for (int k = 0; k < 8; ++k)
        o[k] = (bf16)((x[k][i] - mu[i]) * rs[i] * gr[k] + br[k]);
      *(bf16x8*)&dstb[orow + cb] = o;
    }
  }
}

// ---------------------------------------------------------------------------
// Kernel 3: row LayerNorm(ln2) on cs f32[8192][512] -> hcs bf16. 1 wave/row.
// ---------------------------------------------------------------------------
__global__ __launch_bounds__(256)
void ln2_k(const float* __restrict__ cs, const float* __restrict__ g,
           const float* __restrict__ bb, bf16* __restrict__ hcs)
{
  const int tid = threadIdx.x, wid = tid >> 6, lane = tid & 63;
  const int row = blockIdx.x * 4 + wid;
  const float* x = cs + (size_t)row * 512 + lane * 8;
  float v[8];
  *(f32x4*)&v[0] = *(const f32x4*)&x[0];
  *(f32x4*)&v[4] = *(const f32x4*)&x[4];
  float s = 0.f, ss = 0.f;
#pragma unroll
  for (int k = 0; k < 8; ++k) { s += v[k]; ss += v[k] * v[k]; }
#pragma unroll
  for (int off = 1; off < 64; off <<= 1) {
    s += __shfl_xor(s, off);
    ss += __shfl_xor(ss, off);
  }
  const float mu = s * (1.f / 512.f);
  const float rstd = rsqrtf(ss * (1.f / 512.f) - mu * mu + 1e-5f);
  bf16x8 o;
#pragma unroll
  for (int k = 0; k < 8; ++k) {
    int ch = lane * 8 + k;
    o[k] = (bf16)((v[k] - mu) * rstd * g[ch] + bb[ch]);
  }
  *(bf16x8*)&hcs[(size_t)row * 512 + lane * 8] = o;
}

// ---------------------------------------------------------------------------
// Kernel 4: FC GEMM (M=8192, N=2048, K=512), 2-phase dbuf, GELU epilogue
// staged through padded LDS (stride 132) for full-line coalesced stores.
// ---------------------------------------------------------------------------
__global__ __launch_bounds__(256)
void gemm_fc_k(const bf16* __restrict__ A, const bf16* __restrict__ Bt,
               const float* __restrict__ bias, bf16* __restrict__ fo)
{
  const int K = 512;
  __shared__ __align__(16) char smem[34816];
  bf16* As = (bf16*)smem;            // [2][4096]
  bf16* Bs = (bf16*)(smem + 16384);  // [2][4096]
  const int tid = threadIdx.x;
  const int wid = tid >> 6, lane = tid & 63;
  const int wr = wid >> 1, wc = wid & 1;
  const int ml = lane & 15, kg = (lane >> 4) << 3;
  const int m0 = blockIdx.x * 128, n0 = blockIdx.y * 128;

  const int e0 = wid * 512 + lane * 8;
  const int r0 = e0 >> 5, c0 = e0 & 31;
  const int e1 = e0 + 2048;
  const int r1 = e1 >> 5, c1 = e1 & 31;

  const bf16* Ag = A + (size_t)m0 * K;
  const bf16* Bg = Bt + (size_t)n0 * K;

  f32x4 acc[4][4] = {};

  gload_lds16(Ag + (size_t)r0 * K + c0, As + wid * 512);
  gload_lds16(Ag + (size_t)r1 * K + c1, As + 2048 + wid * 512);
  gload_lds16(Bg + (size_t)r0 * K + c0, Bs + wid * 512);
  gload_lds16(Bg + (size_t)r1 * K + c1, Bs + 2048 + wid * 512);

  int cur = 0;
  for (int k0 = 0; k0 < K; k0 += 32) {
    __syncthreads();
    if (k0 + 32 < K) {
      const int nb = cur ^ 1, kn = k0 + 32;
      gload_lds16(Ag + (size_t)r0 * K + kn + c0, As + nb * 4096 + wid * 512);
      gload_lds16(Ag + (size_t)r1 * K + kn + c1, As + nb * 4096 + 2048 + wid * 512);
      gload_lds16(Bg + (size_t)r0 * K + kn + c0, Bs + nb * 4096 + wid * 512);
      gload_lds16(Bg + (size_t)r1 * K + kn + c1, Bs + nb * 4096 + 2048 + wid * 512);
    }
    bf16x8 af[4], bfr[4];
#pragma unroll
    for (int mf = 0; mf < 4; ++mf)
      af[mf] = *(const bf16x8*)&As[cur * 4096 + (wr * 64 + mf * 16 + ml) * 32 + kg];
#pragma unroll
    for (int nf = 0; nf < 4; ++nf)
      bfr[nf] = *(const bf16x8*)&Bs[cur * 4096 + (wc * 64 + nf * 16 + ml) * 32 + kg];
#pragma unroll
    for (int mf = 0; mf < 4; ++mf)
#pragma unroll
      for (int nf = 0; nf < 4; ++nf)
        acc[mf][nf] = __builtin_amdgcn_mfma_f32_16x16x32_bf16(
            af[mf], bfr[nf], acc[mf][nf], 0, 0, 0);
    cur ^= 1;
  }

  __syncthreads();
  bf16* OT = (bf16*)smem; // [128][132]
  const int jrow0 = (lane >> 4) << 2;
#pragma unroll
  for (int nf = 0; nf < 4; ++nf) {
    const float bv = bias[n0 + wc * 64 + nf * 16 + ml];
#pragma unroll
    for (int mf = 0; mf < 4; ++mf)
#pragma unroll
      for (int j = 0; j < 4; ++j) {
        float x = acc[mf][nf][j] + bv;
        float u = 0.7978845608f * (x + 0.044715f * x * x * x);
        float e = __expf(2.f * u);
        float th = 1.f - 2.f / (e + 1.f);
        OT[(wr * 64 + mf * 16 + jrow0 + j) * 132 + wc * 64 + nf * 16 + ml] =
            (bf16)(0.5f * x * (1.f + th));
      }
  }
  __syncthreads();
#pragma unroll
  for (int it = 0; it < 8; ++it) {
    const int idx = it * 256 + tid;
    const int cg = idx & 15, r = idx >> 4;
    *(bf16x8*)&fo[(size_t)(m0 + r) * 2048 + n0 + cg * 8] =
        *(const bf16x8*)&OT[r * 132 + cg * 8];
  }
}

// ---------------------------------------------------------------------------
// Kernel 4b: in-block split-K GEMM for N=512 stages (O, PR). 512 threads,
// 2 wave-groups x K-half, 2-phase dbuf each. LDS PACKED to 64 KB:
// AS [2][2][4096] @0 (32KB), BS @32KB (32KB), CF f32[128][128] overlays both
// (used only after the post-K-loop barrier) -> 2 blocks/CU.
// ---------------------------------------------------------------------------
enum { EPI_O = 2, EPI_PR = 4 };

template <int EPI>
__global__ __launch_bounds__(512)
void gemmsk_k(const bf16* __restrict__ A, const bf16* __restrict__ Bt,
              const float* __restrict__ bias, const float* res,
              void* out0, int K)
{
  __shared__ __align__(16) char smem[65536];
  bf16*  AS = (bf16*)smem;            // [2 dbuf][2 half][4096] = 32 KB
  bf16*  BS = (bf16*)(smem + 32768);  // 32 KB
  float* CF = (float*)smem;           // 64 KB overlay (post-barrier only)

  const int tid = threadIdx.x;
  const int wid = tid >> 6, lane = tid & 63;
  const int half = wid >> 2, w2 = wid & 3;
  const int wr = w2 >> 1, wc = w2 & 1;
  const int ml = lane & 15, kg = (lane >> 4) << 3;
  const int m0 = blockIdx.x * 128, n0 = blockIdx.y * 128;
  const int Kh = K >> 1;

  const int e0 = w2 * 512 + lane * 8;
  const int r0 = e0 >> 5, c0 = e0 & 31;
  const int e1 = e0 + 2048;
  const int r1 = e1 >> 5, c1 = e1 & 31;

  const bf16* Ag = A + (size_t)m0 * K + half * Kh;
  const bf16* Bg = Bt + (size_t)n0 * K + half * Kh;
  bf16* A0 = AS + half * 4096;
  bf16* B0 = BS + half * 4096;

  f32x4 acc[4][4] = {};

  gload_lds16(Ag + (size_t)r0 * K + c0, A0 + w2 * 512);
  gload_lds16(Ag + (size_t)r1 * K + c1, A0 + 2048 + w2 * 512);
  gload_lds16(Bg + (size_t)r0 * K + c0, B0 + w2 * 512);
  gload_lds16(Bg + (size_t)r1 * K + c1, B0 + 2048 + w2 * 512);

  int cur = 0;
  for (int k0 = 0; k0 < Kh; k0 += 32) {
    __syncthreads();
    if (k0 + 32 < Kh) {
      const int kn = k0 + 32;
      bf16* An = AS + ((cur ^ 1) * 8192) + half * 4096;
      bf16* Bn = BS + ((cur ^ 1) * 8192) + half * 4096;
      gload_lds16(Ag + (size_t)r0 * K + kn + c0, An + w2 * 512);
      gload_lds16(Ag + (size_t)r1 * K + kn + c1, An + 2048 + w2 * 512);
      gload_lds16(Bg + (size_t)r0 * K + kn + c0, Bn + w2 * 512);
      gload_lds16(Bg + (size_t)r1 * K + kn + c1, Bn + 2048 + w2 * 512);
    }
    const bf16* Ac = AS + cur * 8192 + half * 4096;
    const bf16* Bc = BS + cur * 8192 + half * 4096;
    bf16x8 af[4], bfr[4];
#pragma unroll
    for (int mf = 0; mf < 4; ++mf)
      af[mf] = *(const bf16x8*)&Ac[(wr * 64 + mf * 16 + ml) * 32 + kg];
#pragma unroll
    for (int nf = 0; nf < 4; ++nf)
      bfr[nf] = *(const bf16x8*)&Bc[(wc * 64 + nf * 16 + ml) * 32 + kg];
#pragma unroll
    for (int mf = 0; mf < 4; ++mf)
#pragma unroll
      for (int nf = 0; nf < 4; ++nf)
        acc[mf][nf] = __builtin_amdgcn_mfma_f32_16x16x32_bf16(
            af[mf], bfr[nf], acc[mf][nf], 0, 0, 0);
    cur ^= 1;
  }

  const int jrow0 = (lane >> 4) << 2;
  __syncthreads(); // staging dead; CF may overlay AS/BS
  if (half == 0) {
#pragma unroll
    for (int mf = 0; mf < 4; ++mf)
#pragma unroll
      for (int nf = 0; nf < 4; ++nf)
#pragma unroll
        for (int j = 0; j < 4; ++j)
          CF[(wr * 64 + mf * 16 + jrow0 + j) * 128 + wc * 64 + nf * 16 + ml] =
              acc[mf][nf][j];
  }
  __syncthreads();
  if (half == 1) {
#pragma unroll
    for (int nf = 0; nf < 4; ++nf) {
      const int n = n0 + wc * 64 + nf * 16 + ml;
      const float bv = bias[n];
#pragma unroll
      for (int mf = 0; mf < 4; ++mf) {
        const int mbase = m0 + wr * 64 + mf * 16 + jrow0;
        float v4[4];
#pragma unroll
        for (int j = 0; j < 4; ++j)
          v4[j] = acc[mf][nf][j] +
                  CF[(wr * 64 + mf * 16 + jrow0 + j) * 128 + wc * 64 + nf * 16 + ml];
        if constexpr (EPI == EPI_O) {
          float* cs = (float*)out0;
#pragma unroll
          for (int j = 0; j < 4; ++j) {
            const size_t idx = (size_t)(mbase + j) * 512 + n;
            cs[idx] = v4[j] + bv + res[idx];
          }
        } else {
          float* out = (float*)out0;
          const int b = mbase >> 10, t = mbase & 1023;
          const int v = t >> 8, hhh = (t >> 4) & 15, w0 = t & 15;
          f32x4 o;
#pragma unroll
          for (int j = 0; j < 4; ++j)
            o[j] = v4[j] + bv + res[(size_t)(mbase + j) * 512 + n];
          *(f32x4*)&out[(((size_t)v * 8 + b) * 512 + n) * 256 + hhh * 16 + w0] = o;
        }
      }
    }
  }
}

// ---------------------------------------------------------------------------
// Kernel 4c: merged Q + KV projection GEMM, 2-phase dbuf, LDS-staged stores.
// Grid (64, 12): ybl 0-3 Q, 4-7 K, 8-11 V(transposed).
// ---------------------------------------------------------------------------
__global__ __launch_bounds__(256)
void gemm_qkv_k(const bf16* __restrict__ Aq, const bf16* __restrict__ Akv,
                const bf16* __restrict__ WqT, const bf16* __restrict__ WkvT,
                const float* __restrict__ bq, const float* __restrict__ bkv,
                bf16* __restrict__ q_buf, bf16* __restrict__ k_buf,
                bf16* __restrict__ v_t)
{
  const int K = 512;
  __shared__ __align__(16) char smem[34816];
  bf16* As = (bf16*)smem;
  bf16* Bs = (bf16*)(smem + 16384);
  const int tid = threadIdx.x;
  const int wid = tid >> 6, lane = tid & 63;
  const int wr = wid >> 1, wc = wid & 1;
  const int ml = lane & 15, kg = (lane >> 4) << 3;
  const int ybl = blockIdx.y;
  const bool isq = ybl < 4;
  const bf16* A     = isq ? Aq  : Akv;
  const bf16* Bt    = isq ? WqT : WkvT;
  const float* bias = isq ? bq : bkv;
  const int n0 = isq ? (ybl << 7) : ((ybl - 4) << 7);
  const int m0 = blockIdx.x * 128;

  const int e0 = wid * 512 + lane * 8;
  const int r0 = e0 >> 5, c0 = e0 & 31;
  const int e1 = e0 + 2048;
  const int r1 = e1 >> 5, c1 = e1 & 31;

  const bf16* Ag = A + (size_t)m0 * K;
  const bf16* Bg = Bt + (size_t)n0 * K;

  f32x4 acc[4][4] = {};

  gload_lds16(Ag + (size_t)r0 * K + c0, As + wid * 512);
  gload_lds16(Ag + (size_t)r1 * K + c1, As + 2048 + wid * 512);
  gload_lds16(Bg + (size_t)r0 * K + c0, Bs + wid * 512);
  gload_lds16(Bg + (size_t)r1 * K + c1, Bs + 2048 + wid * 512);

  int cur = 0;
  for (int k0 = 0; k0 < K; k0 += 32) {
    __syncthreads();
    if (k0 + 32 < K) {
      const int nb = cur ^ 1, kn = k0 + 32;
      gload_lds16(Ag + (size_t)r0 * K + kn + c0, As + nb * 4096 + wid * 512);
      gload_lds16(Ag + (size_t)r1 * K + kn + c1, As + nb * 4096 + 2048 + wid * 512);
      gload_lds16(Bg + (size_t)r0 * K + kn + c0, Bs + nb * 4096 + wid * 512);
      gload_lds16(Bg + (size_t)r1 * K + kn + c1, Bs + nb * 4096 + 2048 + wid * 512);
    }
    bf16x8 af[4], bfr[4];
#pragma unroll
    for (int mf = 0; mf < 4; ++mf)
      af[mf] = *(const bf16x8*)&As[cur * 4096 + (wr * 64 + mf * 16 + ml) * 32 + kg];
#pragma unroll
    for (int nf = 0; nf < 4; ++nf)
      bfr[nf] = *(const bf16x8*)&Bs[cur * 4096 + (wc * 64 + nf * 16 + ml) * 32 + kg];
#pragma unroll
    for (int mf = 0; mf < 4; ++mf)
#pragma unroll
      for (int nf = 0; nf < 4; ++nf)
        acc[mf][nf] = __builtin_amdgcn_mfma_f32_16x16x32_bf16(
            af[mf], bfr[nf], acc[mf][nf], 0, 0, 0);
    cur ^= 1;
  }

  __syncthreads();
  bf16* OT = (bf16*)smem; // [128][132] padded
  const int jrow0 = (lane >> 4) << 2;
  const int b = m0 >> 10, t0 = m0 & 1023;
  if (ybl < 8) { // Q or K: stage row-major (row=m, col=n)
#pragma unroll
    for (int nf = 0; nf < 4; ++nf) {
      const float bv = bias[n0 + wc * 64 + nf * 16 + ml];
#pragma unroll
      for (int mf = 0; mf < 4; ++mf)
#pragma unroll
        for (int j = 0; j < 4; ++j)
          OT[(wr * 64 + mf * 16 + jrow0 + j) * 132 + wc * 64 + nf * 16 + ml] =
              (bf16)(acc[mf][nf][j] + bv);
    }
    __syncthreads();
    bf16* dst = isq ? q_buf : k_buf;
    const int h0 = n0 >> 6;
#pragma unroll
    for (int it = 0; it < 8; ++it) {
      const int idx = it * 256 + tid;
      const int dg = idx & 7, r = (idx >> 3) & 127, hl = idx >> 10;
      *(bf16x8*)&dst[(((size_t)b * 8 + h0 + hl) * 1024 + t0 + r) * 64 + dg * 8] =
          *(const bf16x8*)&OT[r * 132 + hl * 64 + dg * 8];
    }
  } else { // V: stage col-major for t-contiguous stores
#pragma unroll
    for (int nf = 0; nf < 4; ++nf) {
      const float bv = bias[n0 + wc * 64 + nf * 16 + ml];
#pragma unroll
      for (int mf = 0; mf < 4; ++mf) {
        bf16x4 o;
#pragma unroll
        for (int j = 0; j < 4; ++j) o[j] = (bf16)(acc[mf][nf][j] + bv);
        *(bf16x4*)&OT[(wc * 64 + nf * 16 + ml) * 132 + wr * 64 + mf * 16 + jrow0] = o;
      }
    }
    __syncthreads();
    const int h0 = (n0 - 512) >> 6;
#pragma unroll
    for (int it = 0; it < 8; ++it) {
      const int idx = it * 256 + tid;
      const int og = idx & 15, c = idx >> 4;
      const int hl = c >> 6, d = c & 63;
      *(bf16x8*)&v_t[(((size_t)b * 8 + h0 + hl) * 64 + d) * 1024 + t0 + og * 8] =
          *(const bf16x8*)&OT[c * 132 + og * 8];
    }
  }
}

// ---------------------------------------------------------------------------
// Kernel 5: block-causal flash attention (unchanged from R2-R8).
// ---------------------------------------------------------------------------
__global__ __launch_bounds__(256)
void attn_k(const bf16* __restrict__ qb, const bf16* __restrict__ kb,
            const bf16* __restrict__ vt, bf16* __restrict__ y)
{
  __shared__ bf16 Ks[2][4096];
  __shared__ bf16 Vs[2][4096];
  __shared__ bf16 Ps[4][1024];
  const int tid = threadIdx.x, wid = tid >> 6, lane = tid & 63;
  const int L = blockIdx.x;
  const int xcd = L & 7, chunk = L >> 3;
  const int bh = xcd + ((chunk >> 4) << 3);
  const int qt = 15 - (chunk & 15);
  const int b = bh >> 3, h = bh & 7;
  const int t0 = qt << 6;
  const int ml = lane & 15, hi = lane >> 4, kg = hi << 3;

  const bf16* qrow = qb + ((size_t)bh * 1024 + t0 + wid * 16) * 64;
  bf16x8 aq[2];
  aq[0] = *(const bf16x8*)&qrow[ml * 64 + kg];
  aq[1] = *(const bf16x8*)&qrow[ml * 64 + 32 + kg];

  f32x4 accO[4] = {};
  float lsum[4] = {0.f, 0.f, 0.f, 0.f};

  const int nkt = ((qt >> 2) + 1) << 2;
  const bf16* kbase = kb + (size_t)bh * 1024 * 64;
  const bf16* vbase = vt + (size_t)bh * 64 * 1024;

  const int sr = (wid << 3) + (lane >> 3);
  const int sg = ((lane & 7) ^ ((lane >> 3) & 7)) << 3;
  bf16* pw = &Ps[wid][0];

  {
    gload_lds16(kbase + (size_t)sr * 64 + sg,          &Ks[0][wid * 512]);
    gload_lds16(kbase + (size_t)(sr + 32) * 64 + sg,   &Ks[0][2048 + wid * 512]);
    gload_lds16(vbase + (size_t)sr * 1024 + sg,        &Vs[0][wid * 512]);
    gload_lds16(vbase + (size_t)(sr + 32) * 1024 + sg, &Vs[0][2048 + wid * 512]);
  }

  int cur = 0;
  for (int kt = 0; kt < nkt; ++kt) {
    __syncthreads();
    if (kt + 1 < nkt) {
      const int tk0 = (kt + 1) << 6;
      const int nb = cur ^ 1;
      gload_lds16(kbase + (size_t)(tk0 + sr) * 64 + sg,        &Ks[nb][wid * 512]);
      gload_lds16(kbase + (size_t)(tk0 + sr + 32) * 64 + sg,   &Ks[nb][2048 + wid * 512]);
      gload_lds16(vbase + (size_t)sr * 1024 + tk0 + sg,        &Vs[nb][wid * 512]);
      gload_lds16(vbase + (size_t)(sr + 32) * 1024 + tk0 + sg, &Vs[nb][2048 + wid * 512]);
    }

    f32x4 sa[4] = {};
#pragma unroll
    for (int nf = 0; nf < 4; ++nf) {
      const int row = nf * 16 + ml;
#pragma unroll
      for (int ks = 0; ks < 2; ++ks) {
        const int g = ((ks * 4 + hi) ^ (ml & 7)) << 3;
        bf16x8 bk = *(const bf16x8*)&Ks[cur][row * 64 + g];
        sa[nf] = __builtin_amdgcn_mfma_f32_16x16x32_bf16(aq[ks], bk, sa[nf], 0, 0, 0);
      }
    }

#pragma unroll
    for (int nf = 0; nf < 4; ++nf) {
      const int gp0 = nf * 2 + (ml >> 3);
#pragma unroll
      for (int j = 0; j < 4; ++j) {
        const float p = __expf(sa[nf][j] * 0.125f);
        lsum[j] += p;
        const int prow = (hi << 2) + j;
        pw[prow * 64 + ((gp0 ^ (prow & 7)) << 3) + (ml & 7)] = (bf16)p;
      }
    }

#pragma unroll
    for (int ks = 0; ks < 2; ++ks) {
      const int g = ((ks * 4 + hi) ^ (ml & 7)) << 3;
      bf16x8 pa = *(const bf16x8*)&pw[ml * 64 + g];
#pragma unroll
      for (int df = 0; df < 4; ++df) {
        bf16x8 bv = *(const bf16x8*)&Vs[cur][(df * 16 + ml) * 64 + g];
        accO[df] = __builtin_amdgcn_mfma_f32_16x16x32_bf16(pa, bv, accO[df], 0, 0, 0);
      }
    }
    cur ^= 1;
  }

  float inv[4];
#pragma unroll
  for (int j = 0; j < 4; ++j) {
    float s = lsum[j];
#pragma unroll
    for (int off = 1; off < 16; off <<= 1) s += __shfl_xor(s, off);
    inv[j] = 1.f / s;
  }
#pragma unroll
  for (int df = 0; df < 4; ++df)
#pragma unroll
    for (int j = 0; j < 4; ++j) {
      const int t = t0 + wid * 16 + (hi << 2) + j;
      const int c = h * 64 + df * 16 + ml;
      y[((size_t)b * 1024 + t) * 512 + c] = (bf16)(accO[df][j] * inv[j]);
    }
}

// ---------------------------------------------------------------------------
extern "C" void kernel_launch(void* const* d_in, const int* in_sizes, int n_in,
                              void* d_out, int out_size, void* d_ws, size_t ws_size,
                              hipStream_t stream)
{
  const float* xi    = (const float*)d_in[0];
  const float* xc    = (const float*)d_in[1];
  const float* xj    = (const float*)d_in[2];
  const float* ln1_g = (const float*)d_in[3];
  const float* ln1_b = (const float*)d_in[4];
  const float* ln2_g = (const float*)d_in[5];
  const float* ln2_b = (const float*)d_in[6];
  const float* Wq    = (const float*)d_in[7];
  const float* bq    = (const float*)d_in[8];
  const float* Wkv   = (const float*)d_in[9];
  const float* bkv   = (const float*)d_in[10];
  const float* Wo    = (const float*)d_in[11];
  const float* bo    = (const float*)d_in[12];
  const float* Wfc   = (const float*)d_in[13];
  const float* bfc   = (const float*)d_in[14];
  const float* Wpr   = (const float*)d_in[15];
  const float* bpr   = (const float*)d_in[16];

  char* ws = (char*)d_ws;
  const size_t MB = 1ull << 20;
  bf16*  qs    = (bf16*)(ws + 0);
  bf16*  kvs   = (bf16*)(ws + 8 * MB);
  float* cs0   = (float*)(ws + 16 * MB);
  bf16*  WqT   = (bf16*)(ws + 32 * MB);
  bf16*  WkvT  = (bf16*)(ws + 32 * MB + 512 * 1024);
  bf16*  WoT   = (bf16*)(ws + 33 * MB + 512 * 1024);
  bf16*  WfcT  = (bf16*)(ws + 34 * MB);
  bf16*  WprT  = (bf16*)(ws + 36 * MB);
  bf16*  q_buf = (bf16*)(ws + 38 * MB);
  bf16*  k_buf = (bf16*)(ws + 46 * MB);
  bf16*  v_t   = (bf16*)(ws + 54 * MB);
  bf16*  yb    = (bf16*)(ws + 0);
  bf16*  hcs   = (bf16*)(ws + 8 * MB);
  bf16*  fcact = (bf16*)(ws + 38 * MB);
  float* cs    = cs0;

  prep_k<<<dim3(4608), 256, 0, stream>>>(Wq, Wkv, Wo, Wfc, Wpr,
                                         WqT, WkvT, WoT, WfcT, WprT,
                                         xi, xj, xc, ln1_g, ln1_b, qs, kvs, cs0);

  gemm_qkv_k<<<dim3(64, 12), 256, 0, stream>>>(qs, kvs, WqT, WkvT, bq, bkv,
                                               q_buf, k_buf, v_t);

  attn_k<<<dim3(1024), 256, 0, stream>>>(q_buf, k_buf, v_t, yb);

  gemmsk_k<EPI_O><<<dim3(64, 4), 512, 0, stream>>>(yb, WoT, bo, cs0,
                                                   (void*)cs, 512);

  ln2_k<<<dim3(2048), 256, 0, stream>>>(cs, ln2_g, ln2_b, hcs);

  gemm_fc_k<<<dim3(64, 16), 256, 0, stream>>>(hcs, WfcT, bfc, fcact);

  gemmsk_k<EPI_PR><<<dim3(64, 4), 512, 0, stream>>>(fcact, WprT, bpr, cs,
                                                    d_out, 2048);

  (void)in_sizes; (void)n_in; (void)out_size; (void)ws_size;
}

// Round 10
// 169.916 us; speedup vs baseline: 1.0750x; 1.0750x over previous
//
#include <hip/hip_runtime.h>
#include <hip/hip_bf16.h>
#include <math.h>

// ---------------------------------------------------------------------------
// CrossCausalAttentionBlock on MI355X (gfx950)
// B=8, T=1024 (V=4 blocks of 256), C=512, NH=8, hd=64
// R10: gemmsk BM 128->64, grid (128,4)=512 blocks = 2/CU (R9's LDS packing
//      was grid-limited at 1/CU); cs residual bf16 end-to-end (-40MB HBM);
//      attn MFMA setprio (T5).
// ---------------------------------------------------------------------------

typedef __bf16 bf16;
typedef __bf16 bf16x8 __attribute__((ext_vector_type(8)));
typedef __bf16 bf16x4 __attribute__((ext_vector_type(4)));
typedef float  f32x4  __attribute__((ext_vector_type(4)));

__device__ __forceinline__ void gload_lds16(const void* g, void* l) {
  __builtin_amdgcn_global_load_lds(
      (__attribute__((address_space(1))) void*)(g),
      (__attribute__((address_space(3))) void*)(l), 16, 0, 0);
}

// ---------------------------------------------------------------------------
// Kernel 1: prep = weight converts (blocks 0..3071) + gather+LN1 (3072..4607)
// LN register-resident, bf16x8 vector stores for all three outputs.
// ---------------------------------------------------------------------------
__global__ __launch_bounds__(256)
void prep_k(const float* __restrict__ Wq, const float* __restrict__ Wkv,
            const float* __restrict__ Wo, const float* __restrict__ Wfc,
            const float* __restrict__ Wpr,
            bf16* __restrict__ WqT, bf16* __restrict__ WkvT,
            bf16* __restrict__ WoT, bf16* __restrict__ WfcT,
            bf16* __restrict__ WprT,
            const float* __restrict__ xi, const float* __restrict__ xj,
            const float* __restrict__ xc,
            const float* __restrict__ g, const float* __restrict__ bb,
            bf16* __restrict__ qs, bf16* __restrict__ kvs,
            bf16* __restrict__ csb)
{
  __shared__ float tt[32][33];
  __shared__ float red[4][32];
  const int t = blockIdx.x;
  const int tid = threadIdx.x;
  if (t < 3072) { // ---- weight transpose-convert, 32x32 tiles
    const float* W; bf16* Wt; int K, N, lognx, tl;
    if (t < 256)       { W = Wq;  Wt = WqT;  K = 512;  N = 512;  lognx = 4; tl = t; }
    else if (t < 768)  { W = Wkv; Wt = WkvT; K = 512;  N = 1024; lognx = 5; tl = t - 256; }
    else if (t < 1024) { W = Wo;  Wt = WoT;  K = 512;  N = 512;  lognx = 4; tl = t - 768; }
    else if (t < 2048) { W = Wfc; Wt = WfcT; K = 512;  N = 2048; lognx = 6; tl = t - 1024; }
    else               { W = Wpr; Wt = WprT; K = 2048; N = 512;  lognx = 4; tl = t - 2048; }
    const int bx = tl & ((1 << lognx) - 1), by = tl >> lognx;
    const int x = tid & 31, y = tid >> 5;
    const int n0 = bx << 5, k0 = by << 5;
#pragma unroll
    for (int yy = y; yy < 32; yy += 8)
      tt[yy][x] = W[(size_t)(k0 + yy) * N + n0 + x];
    __syncthreads();
#pragma unroll
    for (int yy = y; yy < 32; yy += 8)
      Wt[(size_t)(n0 + yy) * K + k0 + x] = (bf16)tt[x][yy];
    return;
  }
  // ---- gather [v,b,c,h,w] -> [b,t,c] + LN1, register-resident
  const int u = t - 3072;
  const int sel = u >> 9, bid = u & 511;
  const int hh = bid & 15, b = (bid >> 4) & 7, v = bid >> 7;
  const float* src = (sel == 0) ? xi : ((sel == 1) ? xj : xc);
  const size_t base = ((size_t)(v * 8 + b) * 512) * 256 + (size_t)hh * 16;
  const int q = tid & 3, chb = tid >> 2;
  const int wid = tid >> 6, lane = tid & 63;
  const int cb = chb << 3;

  float gr[8], br[8];
  *(f32x4*)&gr[0] = *(const f32x4*)&g[cb];
  *(f32x4*)&gr[4] = *(const f32x4*)&g[cb + 4];
  *(f32x4*)&br[0] = *(const f32x4*)&bb[cb];
  *(f32x4*)&br[4] = *(const f32x4*)&bb[cb + 4];

  f32x4 x[8];
#pragma unroll
  for (int k = 0; k < 8; ++k)
    x[k] = *(const f32x4*)&src[base + (size_t)(cb + k) * 256 + (q << 2)];

  float s[4] = {0.f, 0.f, 0.f, 0.f}, ss[4] = {0.f, 0.f, 0.f, 0.f};
#pragma unroll
  for (int k = 0; k < 8; ++k)
#pragma unroll
    for (int i = 0; i < 4; ++i) {
      s[i] += x[k][i];
      ss[i] += x[k][i] * x[k][i];
    }
#pragma unroll
  for (int off = 4; off < 64; off <<= 1)
#pragma unroll
    for (int i = 0; i < 4; ++i) {
      s[i] += __shfl_xor(s[i], off);
      ss[i] += __shfl_xor(ss[i], off);
    }
  if (lane < 16) {
    red[wid][(lane & 3) * 4 + (lane >> 2)]      = s[lane >> 2];
    red[wid][16 + (lane & 3) * 4 + (lane >> 2)] = ss[lane >> 2];
  }
  __syncthreads();
  float mu[4], rs[4];
#pragma unroll
  for (int i = 0; i < 4; ++i) {
    const int e = q * 4 + i;
    float st  = red[0][e] + red[1][e] + red[2][e] + red[3][e];
    float sst = red[0][16 + e] + red[1][16 + e] + red[2][16 + e] + red[3][16 + e];
    mu[i] = st * (1.f / 512.f);
    rs[i] = rsqrtf(sst * (1.f / 512.f) - mu[i] * mu[i] + 1e-5f);
  }
  const int tkb = v * 256 + hh * 16 + (q << 2);
  bf16* dstb = (sel == 0) ? qs : ((sel == 1) ? kvs : csb);
#pragma unroll
  for (int i = 0; i < 4; ++i) {
    const size_t orow = ((size_t)b * 1024 + tkb + i) * 512;
    bf16x8 o;
#pragma unroll
    for (int k = 0; k < 8; ++k)
      o[k] = (bf16)((x[k][i] - mu[i]) * rs[i] * gr[k] + br[k]);
    *(bf16x8*)&dstb[orow + cb] = o;
  }
}

// ---------------------------------------------------------------------------
// Kernel 3: row LayerNorm(ln2) on cs bf16[8192][512] -> hcs bf16. 1 wave/row.
// ---------------------------------------------------------------------------
__global__ __launch_bounds__(256)
void ln2_k(const bf16* __restrict__ cs, const float* __restrict__ g,
           const float* __restrict__ bb, bf16* __restrict__ hcs)
{
  const int tid = threadIdx.x, wid = tid >> 6, lane = tid & 63;
  const int row = blockIdx.x * 4 + wid;
  const bf16x8 v8 = *(const bf16x8*)&cs[(size_t)row * 512 + lane * 8];
  float v[8];
#pragma unroll
  for (int k = 0; k < 8; ++k) v[k] = (float)v8[k];
  float s = 0.f, ss = 0.f;
#pragma unroll
  for (int k = 0; k < 8; ++k) { s += v[k]; ss += v[k] * v[k]; }
#pragma unroll
  for (int off = 1; off < 64; off <<= 1) {
    s += __shfl_xor(s, off);
    ss += __shfl_xor(ss, off);
  }
  const float mu = s * (1.f / 512.f);
  const float rstd = rsqrtf(ss * (1.f / 512.f) - mu * mu + 1e-5f);
  bf16x8 o;
#pragma unroll
  for (int k = 0; k < 8; ++k) {
    int ch = lane * 8 + k;
    o[k] = (bf16)((v[k] - mu) * rstd * g[ch] + bb[ch]);
  }
  *(bf16x8*)&hcs[(size_t)row * 512 + lane * 8] = o;
}

// ---------------------------------------------------------------------------
// Kernel 4: FC GEMM (M=8192, N=2048, K=512), 2-phase dbuf, GELU epilogue
// staged through padded LDS (stride 132) for full-line coalesced stores.
// ---------------------------------------------------------------------------
__global__ __launch_bounds__(256)
void gemm_fc_k(const bf16* __restrict__ A, const bf16* __restrict__ Bt,
               const float* __restrict__ bias, bf16* __restrict__ fo)
{
  const int K = 512;
  __shared__ __align__(16) char smem[34816];
  bf16* As = (bf16*)smem;            // [2][4096]
  bf16* Bs = (bf16*)(smem + 16384);  // [2][4096]
  const int tid = threadIdx.x;
  const int wid = tid >> 6, lane = tid & 63;
  const int wr = wid >> 1, wc = wid & 1;
  const int ml = lane & 15, kg = (lane >> 4) << 3;
  const int m0 = blockIdx.x * 128, n0 = blockIdx.y * 128;

  const int e0 = wid * 512 + lane * 8;
  const int r0 = e0 >> 5, c0 = e0 & 31;
  const int e1 = e0 + 2048;
  const int r1 = e1 >> 5, c1 = e1 & 31;

  const bf16* Ag = A + (size_t)m0 * K;
  const bf16* Bg = Bt + (size_t)n0 * K;

  f32x4 acc[4][4] = {};

  gload_lds16(Ag + (size_t)r0 * K + c0, As + wid * 512);
  gload_lds16(Ag + (size_t)r1 * K + c1, As + 2048 + wid * 512);
  gload_lds16(Bg + (size_t)r0 * K + c0, Bs + wid * 512);
  gload_lds16(Bg + (size_t)r1 * K + c1, Bs + 2048 + wid * 512);

  int cur = 0;
  for (int k0 = 0; k0 < K; k0 += 32) {
    __syncthreads();
    if (k0 + 32 < K) {
      const int nb = cur ^ 1, kn = k0 + 32;
      gload_lds16(Ag + (size_t)r0 * K + kn + c0, As + nb * 4096 + wid * 512);
      gload_lds16(Ag + (size_t)r1 * K + kn + c1, As + nb * 4096 + 2048 + wid * 512);
      gload_lds16(Bg + (size_t)r0 * K + kn + c0, Bs + nb * 4096 + wid * 512);
      gload_lds16(Bg + (size_t)r1 * K + kn + c1, Bs + nb * 4096 + 2048 + wid * 512);
    }
    bf16x8 af[4], bfr[4];
#pragma unroll
    for (int mf = 0; mf < 4; ++mf)
      af[mf] = *(const bf16x8*)&As[cur * 4096 + (wr * 64 + mf * 16 + ml) * 32 + kg];
#pragma unroll
    for (int nf = 0; nf < 4; ++nf)
      bfr[nf] = *(const bf16x8*)&Bs[cur * 4096 + (wc * 64 + nf * 16 + ml) * 32 + kg];
#pragma unroll
    for (int mf = 0; mf < 4; ++mf)
#pragma unroll
      for (int nf = 0; nf < 4; ++nf)
        acc[mf][nf] = __builtin_amdgcn_mfma_f32_16x16x32_bf16(
            af[mf], bfr[nf], acc[mf][nf], 0, 0, 0);
    cur ^= 1;
  }

  __syncthreads();
  bf16* OT = (bf16*)smem; // [128][132]
  const int jrow0 = (lane >> 4) << 2;
#pragma unroll
  for (int nf = 0; nf < 4; ++nf) {
    const float bv = bias[n0 + wc * 64 + nf * 16 + ml];
#pragma unroll
    for (int mf = 0; mf < 4; ++mf)
#pragma unroll
      for (int j = 0; j < 4; ++j) {
        float x = acc[mf][nf][j] + bv;
        float u = 0.7978845608f * (x + 0.044715f * x * x * x);
        float e = __expf(2.f * u);
        float th = 1.f - 2.f / (e + 1.f);
        OT[(wr * 64 + mf * 16 + jrow0 + j) * 132 + wc * 64 + nf * 16 + ml] =
            (bf16)(0.5f * x * (1.f + th));
      }
  }
  __syncthreads();
#pragma unroll
  for (int it = 0; it < 8; ++it) {
    const int idx = it * 256 + tid;
    const int cg = idx & 15, r = idx >> 4;
    *(bf16x8*)&fo[(size_t)(m0 + r) * 2048 + n0 + cg * 8] =
        *(const bf16x8*)&OT[r * 132 + cg * 8];
  }
}

// ---------------------------------------------------------------------------
// Kernel 4b: in-block split-K GEMM for N=512 stages (O, PR). BM=64, BN=128,
// grid (128,4) = 512 blocks = 2/CU. 512 threads = 2 K-half groups x 4 waves
// (wave tile 32x64, acc[2][4]); 2-phase dbuf; CF combine overlays staging.
// LDS: AS 16KB @0, BS 32KB @16KB, CF f32[64][128] 32KB @0 (post-barrier).
// ---------------------------------------------------------------------------
enum { EPI_O = 2, EPI_PR = 4 };

template <int EPI>
__global__ __launch_bounds__(512)
void gemmsk_k(const bf16* __restrict__ A, const bf16* __restrict__ Bt,
              const float* __restrict__ bias, const bf16* res,
              void* out0, int K)
{
  __shared__ __align__(16) char smem[49152];
  bf16*  AS = (bf16*)smem;            // [2 dbuf][2 half][2048] = 16 KB
  bf16*  BS = (bf16*)(smem + 16384);  // [2 dbuf][2 half][4096] = 32 KB
  float* CF = (float*)smem;           // f32[64][128] = 32 KB overlay

  const int tid = threadIdx.x;
  const int wid = tid >> 6, lane = tid & 63;
  const int half = wid >> 2, w2 = wid & 3;
  const int wr = w2 >> 1, wc = w2 & 1;
  const int ml = lane & 15, kg = (lane >> 4) << 3;
  const int m0 = blockIdx.x * 64, n0 = blockIdx.y * 128;
  const int Kh = K >> 1;

  const int eA = w2 * 512 + lane * 8;
  const int rA = eA >> 5, cA = eA & 31;
  const int eB0 = (w2 * 2) * 512 + lane * 8;
  const int rB0 = eB0 >> 5, cB0 = eB0 & 31;
  const int eB1 = eB0 + 512;
  const int rB1 = eB1 >> 5, cB1 = eB1 & 31;

  const bf16* Ag = A + (size_t)m0 * K + half * Kh;
  const bf16* Bg = Bt + (size_t)n0 * K + half * Kh;

  f32x4 acc[2][4] = {};

  // prologue: stage tile 0
  gload_lds16(Ag + (size_t)rA * K + cA, AS + half * 2048 + w2 * 512);
  gload_lds16(Bg + (size_t)rB0 * K + cB0, BS + half * 4096 + (w2 * 2) * 512);
  gload_lds16(Bg + (size_t)rB1 * K + cB1, BS + half * 4096 + (w2 * 2 + 1) * 512);

  int cur = 0;
  for (int k0 = 0; k0 < Kh; k0 += 32) {
    __syncthreads();
    if (k0 + 32 < Kh) {
      const int kn = k0 + 32, nb = cur ^ 1;
      gload_lds16(Ag + (size_t)rA * K + kn + cA,
                  AS + nb * 4096 + half * 2048 + w2 * 512);
      gload_lds16(Bg + (size_t)rB0 * K + kn + cB0,
                  BS + nb * 8192 + half * 4096 + (w2 * 2) * 512);
      gload_lds16(Bg + (size_t)rB1 * K + kn + cB1,
                  BS + nb * 8192 + half * 4096 + (w2 * 2 + 1) * 512);
    }
    const bf16* Ac = AS + cur * 4096 + half * 2048;
    const bf16* Bc = BS + cur * 8192 + half * 4096;
    bf16x8 af[2], bfr[4];
#pragma unroll
    for (int mf = 0; mf < 2; ++mf)
      af[mf] = *(const bf16x8*)&Ac[(wr * 32 + mf * 16 + ml) * 32 + kg];
#pragma unroll
    for (int nf = 0; nf < 4; ++nf)
      bfr[nf] = *(const bf16x8*)&Bc[(wc * 64 + nf * 16 + ml) * 32 + kg];
#pragma unroll
    for (int mf = 0; mf < 2; ++mf)
#pragma unroll
      for (int nf = 0; nf < 4; ++nf)
        acc[mf][nf] = __builtin_amdgcn_mfma_f32_16x16x32_bf16(
            af[mf], bfr[nf], acc[mf][nf], 0, 0, 0);
    cur ^= 1;
  }

  const int jrow0 = (lane >> 4) << 2;
  __syncthreads(); // staging dead; CF may overlay AS/BS
  if (half == 0) {
#pragma unroll
    for (int mf = 0; mf < 2; ++mf)
#pragma unroll
      for (int nf = 0; nf < 4; ++nf)
#pragma unroll
        for (int j = 0; j < 4; ++j)
          CF[(wr * 32 + mf * 16 + jrow0 + j) * 128 + wc * 64 + nf * 16 + ml] =
              acc[mf][nf][j];
  }
  __syncthreads();
  if (half == 1) {
#pragma unroll
    for (int nf = 0; nf < 4; ++nf) {
      const int n = n0 + wc * 64 + nf * 16 + ml;
      const float bv = bias[n];
#pragma unroll
      for (int mf = 0; mf < 2; ++mf) {
        const int mbase = m0 + wr * 32 + mf * 16 + jrow0;
        float v4[4];
#pragma unroll
        for (int j = 0; j < 4; ++j)
          v4[j] = acc[mf][nf][j] +
                  CF[(wr * 32 + mf * 16 + jrow0 + j) * 128 + wc * 64 + nf * 16 + ml];
        if constexpr (EPI == EPI_O) {
          bf16* cs = (bf16*)out0; // in-place with res
#pragma unroll
          for (int j = 0; j < 4; ++j) {
            const size_t idx = (size_t)(mbase + j) * 512 + n;
            cs[idx] = (bf16)(v4[j] + bv + (float)res[idx]);
          }
        } else {
          float* out = (float*)out0;
          const int b = mbase >> 10, t = mbase & 1023;
          const int v = t >> 8, hhh = (t >> 4) & 15, w0 = t & 15;
          f32x4 o;
#pragma unroll
          for (int j = 0; j < 4; ++j)
            o[j] = v4[j] + bv + (float)res[(size_t)(mbase + j) * 512 + n];
          *(f32x4*)&out[(((size_t)v * 8 + b) * 512 + n) * 256 + hhh * 16 + w0] = o;
        }
      }
    }
  }
}

// ---------------------------------------------------------------------------
// Kernel 4c: merged Q + KV projection GEMM, 2-phase dbuf, LDS-staged stores.
// Grid (64, 12): ybl 0-3 Q, 4-7 K, 8-11 V(transposed).
// ---------------------------------------------------------------------------
__global__ __launch_bounds__(256)
void gemm_qkv_k(const bf16* __restrict__ Aq, const bf16* __restrict__ Akv,
                const bf16* __restrict__ WqT, const bf16* __restrict__ WkvT,
                const float* __restrict__ bq, const float* __restrict__ bkv,
                bf16* __restrict__ q_buf, bf16* __restrict__ k_buf,
                bf16* __restrict__ v_t)
{
  const int K = 512;
  __shared__ __align__(16) char smem[34816];
  bf16* As = (bf16*)smem;
  bf16* Bs = (bf16*)(smem + 16384);
  const int tid = threadIdx.x;
  const int wid = tid >> 6, lane = tid & 63;
  const int wr = wid >> 1, wc = wid & 1;
  const int ml = lane & 15, kg = (lane >> 4) << 3;
  const int ybl = blockIdx.y;
  const bool isq = ybl < 4;
  const bf16* A     = isq ? Aq  : Akv;
  const bf16* Bt    = isq ? WqT : WkvT;
  const float* bias = isq ? bq : bkv;
  const int n0 = isq ? (ybl << 7) : ((ybl - 4) << 7);
  const int m0 = blockIdx.x * 128;

  const int e0 = wid * 512 + lane * 8;
  const int r0 = e0 >> 5, c0 = e0 & 31;
  const int e1 = e0 + 2048;
  const int r1 = e1 >> 5, c1 = e1 & 31;

  const bf16* Ag = A + (size_t)m0 * K;
  const bf16* Bg = Bt + (size_t)n0 * K;

  f32x4 acc[4][4] = {};

  gload_lds16(Ag + (size_t)r0 * K + c0, As + wid * 512);
  gload_lds16(Ag + (size_t)r1 * K + c1, As + 2048 + wid * 512);
  gload_lds16(Bg + (size_t)r0 * K + c0, Bs + wid * 512);
  gload_lds16(Bg + (size_t)r1 * K + c1, Bs + 2048 + wid * 512);

  int cur = 0;
  for (int k0 = 0; k0 < K; k0 += 32) {
    __syncthreads();
    if (k0 + 32 < K) {
      const int nb = cur ^ 1, kn = k0 + 32;
      gload_lds16(Ag + (size_t)r0 * K + kn + c0, As + nb * 4096 + wid * 512);
      gload_lds16(Ag + (size_t)r1 * K + kn + c1, As + nb * 4096 + 2048 + wid * 512);
      gload_lds16(Bg + (size_t)r0 * K + kn + c0, Bs + nb * 4096 + wid * 512);
      gload_lds16(Bg + (size_t)r1 * K + kn + c1, Bs + nb * 4096 + 2048 + wid * 512);
    }
    bf16x8 af[4], bfr[4];
#pragma unroll
    for (int mf = 0; mf < 4; ++mf)
      af[mf] = *(const bf16x8*)&As[cur * 4096 + (wr * 64 + mf * 16 + ml) * 32 + kg];
#pragma unroll
    for (int nf = 0; nf < 4; ++nf)
      bfr[nf] = *(const bf16x8*)&Bs[cur * 4096 + (wc * 64 + nf * 16 + ml) * 32 + kg];
#pragma unroll
    for (int mf = 0; mf < 4; ++mf)
#pragma unroll
      for (int nf = 0; nf < 4; ++nf)
        acc[mf][nf] = __builtin_amdgcn_mfma_f32_16x16x32_bf16(
            af[mf], bfr[nf], acc[mf][nf], 0, 0, 0);
    cur ^= 1;
  }

  __syncthreads();
  bf16* OT = (bf16*)smem; // [128][132] padded
  const int jrow0 = (lane >> 4) << 2;
  const int b = m0 >> 10, t0 = m0 & 1023;
  if (ybl < 8) { // Q or K: stage row-major (row=m, col=n)
#pragma unroll
    for (int nf = 0; nf < 4; ++nf) {
      const float bv = bias[n0 + wc * 64 + nf * 16 + ml];
#pragma unroll
      for (int mf = 0; mf < 4; ++mf)
#pragma unroll
        for (int j = 0; j < 4; ++j)
          OT[(wr * 64 + mf * 16 + jrow0 + j) * 132 + wc * 64 + nf * 16 + ml] =
              (bf16)(acc[mf][nf][j] + bv);
    }
    __syncthreads();
    bf16* dst = isq ? q_buf : k_buf;
    const int h0 = n0 >> 6;
#pragma unroll
    for (int it = 0; it < 8; ++it) {
      const int idx = it * 256 + tid;
      const int dg = idx & 7, r = (idx >> 3) & 127, hl = idx >> 10;
      *(bf16x8*)&dst[(((size_t)b * 8 + h0 + hl) * 1024 + t0 + r) * 64 + dg * 8] =
          *(const bf16x8*)&OT[r * 132 + hl * 64 + dg * 8];
    }
  } else { // V: stage col-major for t-contiguous stores
#pragma unroll
    for (int nf = 0; nf < 4; ++nf) {
      const float bv = bias[n0 + wc * 64 + nf * 16 + ml];
#pragma unroll
      for (int mf = 0; mf < 4; ++mf) {
        bf16x4 o;
#pragma unroll
        for (int j = 0; j < 4; ++j) o[j] = (bf16)(acc[mf][nf][j] + bv);
        *(bf16x4*)&OT[(wc * 64 + nf * 16 + ml) * 132 + wr * 64 + mf * 16 + jrow0] = o;
      }
    }
    __syncthreads();
    const int h0 = (n0 - 512) >> 6;
#pragma unroll
    for (int it = 0; it < 8; ++it) {
      const int idx = it * 256 + tid;
      const int og = idx & 15, c = idx >> 4;
      const int hl = c >> 6, d = c & 63;
      *(bf16x8*)&v_t[(((size_t)b * 8 + h0 + hl) * 64 + d) * 1024 + t0 + og * 8] =
          *(const bf16x8*)&OT[c * 132 + og * 8];
    }
  }
}

// ---------------------------------------------------------------------------
// Kernel 5: block-causal flash attention (+ T5 setprio around MFMA clusters).
// ---------------------------------------------------------------------------
__global__ __launch_bounds__(256)
void attn_k(const bf16* __restrict__ qb, const bf16* __restrict__ kb,
            const bf16* __restrict__ vt, bf16* __restrict__ y)
{
  __shared__ bf16 Ks[2][4096];
  __shared__ bf16 Vs[2][4096];
  __shared__ bf16 Ps[4][1024];
  const int tid = threadIdx.x, wid = tid >> 6, lane = tid & 63;
  const int L = blockIdx.x;
  const int xcd = L & 7, chunk = L >> 3;
  const int bh = xcd + ((chunk >> 4) << 3);
  const int qt = 15 - (chunk & 15);
  const int b = bh >> 3, h = bh & 7;
  const int t0 = qt << 6;
  const int ml = lane & 15, hi = lane >> 4, kg = hi << 3;

  const bf16* qrow = qb + ((size_t)bh * 1024 + t0 + wid * 16) * 64;
  bf16x8 aq[2];
  aq[0] = *(const bf16x8*)&qrow[ml * 64 + kg];
  aq[1] = *(const bf16x8*)&qrow[ml * 64 + 32 + kg];

  f32x4 accO[4] = {};
  float lsum[4] = {0.f, 0.f, 0.f, 0.f};

  const int nkt = ((qt >> 2) + 1) << 2;
  const bf16* kbase = kb + (size_t)bh * 1024 * 64;
  const bf16* vbase = vt + (size_t)bh * 64 * 1024;

  const int sr = (wid << 3) + (lane >> 3);
  const int sg = ((lane & 7) ^ ((lane >> 3) & 7)) << 3;
  bf16* pw = &Ps[wid][0];

  {
    gload_lds16(kbase + (size_t)sr * 64 + sg,          &Ks[0][wid * 512]);
    gload_lds16(kbase + (size_t)(sr + 32) * 64 + sg,   &Ks[0][2048 + wid * 512]);
    gload_lds16(vbase + (size_t)sr * 1024 + sg,        &Vs[0][wid * 512]);
    gload_lds16(vbase + (size_t)(sr + 32) * 1024 + sg, &Vs[0][2048 + wid * 512]);
  }

  int cur = 0;
  for (int kt = 0; kt < nkt; ++kt) {
    __syncthreads();
    if (kt + 1 < nkt) {
      const int tk0 = (kt + 1) << 6;
      const int nb = cur ^ 1;
      gload_lds16(kbase + (size_t)(tk0 + sr) * 64 + sg,        &Ks[nb][wid * 512]);
      gload_lds16(kbase + (size_t)(tk0 + sr + 32) * 64 + sg,   &Ks[nb][2048 + wid * 512]);
      gload_lds16(vbase + (size_t)sr * 1024 + tk0 + sg,        &Vs[nb][wid * 512]);
      gload_lds16(vbase + (size_t)(sr + 32) * 1024 + tk0 + sg, &Vs[nb][2048 + wid * 512]);
    }

    f32x4 sa[4] = {};
    __builtin_amdgcn_s_setprio(1);
#pragma unroll
    for (int nf = 0; nf < 4; ++nf) {
      const int row = nf * 16 + ml;
#pragma unroll
      for (int ks = 0; ks < 2; ++ks) {
        const int g = ((ks * 4 + hi) ^ (ml & 7)) << 3;
        bf16x8 bk = *(const bf16x8*)&Ks[cur][row * 64 + g];
        sa[nf] = __builtin_amdgcn_mfma_f32_16x16x32_bf16(aq[ks], bk, sa[nf], 0, 0, 0);
      }
    }
    __builtin_amdgcn_s_setprio(0);

#pragma unroll
    for (int nf = 0; nf < 4; ++nf) {
      const int gp0 = nf * 2 + (ml >> 3);
#pragma unroll
      for (int j = 0; j < 4; ++j) {
        const float p = __expf(sa[nf][j] * 0.125f);
        lsum[j] += p;
        const int prow = (hi << 2) + j;
        pw[prow * 64 + ((gp0 ^ (prow & 7)) << 3) + (ml & 7)] = (bf16)p;
      }
    }

    __builtin_amdgcn_s_setprio(1);
#pragma unroll
    for (int ks = 0; ks < 2; ++ks) {
      const int g = ((ks * 4 + hi) ^ (ml & 7)) << 3;
      bf16x8 pa = *(const bf16x8*)&pw[ml * 64 + g];
#pragma unroll
      for (int df = 0; df < 4; ++df) {
        bf16x8 bv = *(const bf16x8*)&Vs[cur][(df * 16 + ml) * 64 + g];
        accO[df] = __builtin_amdgcn_mfma_f32_16x16x32_bf16(pa, bv, accO[df], 0, 0, 0);
      }
    }
    __builtin_amdgcn_s_setprio(0);
    cur ^= 1;
  }

  float inv[4];
#pragma unroll
  for (int j = 0; j < 4; ++j) {
    float s = lsum[j];
#pragma unroll
    for (int off = 1; off < 16; off <<= 1) s += __shfl_xor(s, off);
    inv[j] = 1.f / s;
  }
#pragma unroll
  for (int df = 0; df < 4; ++df)
#pragma unroll
    for (int j = 0; j < 4; ++j) {
      const int t = t0 + wid * 16 + (hi << 2) + j;
      const int c = h * 64 + df * 16 + ml;
      y[((size_t)b * 1024 + t) * 512 + c] = (bf16)(accO[df][j] * inv[j]);
    }
}

// ---------------------------------------------------------------------------
extern "C" void kernel_launch(void* const* d_in, const int* in_sizes, int n_in,
                              void* d_out, int out_size, void* d_ws, size_t ws_size,
                              hipStream_t stream)
{
  const float* xi    = (const float*)d_in[0];
  const float* xc    = (const float*)d_in[1];
  const float* xj    = (const float*)d_in[2];
  const float* ln1_g = (const float*)d_in[3];
  const float* ln1_b = (const float*)d_in[4];
  const float* ln2_g = (const float*)d_in[5];
  const float* ln2_b = (const float*)d_in[6];
  const float* Wq    = (const float*)d_in[7];
  const float* bq    = (const float*)d_in[8];
  const float* Wkv   = (const float*)d_in[9];
  const float* bkv   = (const float*)d_in[10];
  const float* Wo    = (const float*)d_in[11];
  const float* bo    = (const float*)d_in[12];
  const float* Wfc   = (const float*)d_in[13];
  const float* bfc   = (const float*)d_in[14];
  const float* Wpr   = (const float*)d_in[15];
  const float* bpr   = (const float*)d_in[16];

  char* ws = (char*)d_ws;
  const size_t MB = 1ull << 20;
  bf16*  qs    = (bf16*)(ws + 0);                  // 8 MB
  bf16*  kvs   = (bf16*)(ws + 8 * MB);             // 8 MB
  bf16*  csb   = (bf16*)(ws + 16 * MB);            // 8 MB (bf16 residual, in-place)
  bf16*  WqT   = (bf16*)(ws + 32 * MB);
  bf16*  WkvT  = (bf16*)(ws + 32 * MB + 512 * 1024);
  bf16*  WoT   = (bf16*)(ws + 33 * MB + 512 * 1024);
  bf16*  WfcT  = (bf16*)(ws + 34 * MB);
  bf16*  WprT  = (bf16*)(ws + 36 * MB);
  bf16*  q_buf = (bf16*)(ws + 38 * MB);
  bf16*  k_buf = (bf16*)(ws + 46 * MB);
  bf16*  v_t   = (bf16*)(ws + 54 * MB);
  bf16*  yb    = (bf16*)(ws + 0);                  // reuse qs
  bf16*  hcs   = (bf16*)(ws + 8 * MB);             // reuse kvs
  bf16*  fcact = (bf16*)(ws + 38 * MB);            // reuse q/k/v

  prep_k<<<dim3(4608), 256, 0, stream>>>(Wq, Wkv, Wo, Wfc, Wpr,
                                         WqT, WkvT, WoT, WfcT, WprT,
                                         xi, xj, xc, ln1_g, ln1_b, qs, kvs, csb);

  gemm_qkv_k<<<dim3(64, 12), 256, 0, stream>>>(qs, kvs, WqT, WkvT, bq, bkv,
                                               q_buf, k_buf, v_t);

  attn_k<<<dim3(1024), 256, 0, stream>>>(q_buf, k_buf, v_t, yb);

  gemmsk_k<EPI_O><<<dim3(128, 4), 512, 0, stream>>>(yb, WoT, bo, csb,
                                                    (void*)csb, 512);

  ln2_k<<<dim3(2048), 256, 0, stream>>>(csb, ln2_g, ln2_b, hcs);

  gemm_fc_k<<<dim3(64, 16), 256, 0, stream>>>(hcs, WfcT, bfc, fcact);

  gemmsk_k<EPI_PR><<<dim3(128, 4), 512, 0, stream>>>(fcact, WprT, bpr, csb,
                                                     d_out, 2048);

  (void)in_sizes; (void)n_in; (void)out_size; (void)ws_size;
}

// Round 11
// 162.599 us; speedup vs baseline: 1.1234x; 1.0450x over previous
//
#include <hip/hip_runtime.h>
#include <hip/hip_bf16.h>
#include <math.h>

// ---------------------------------------------------------------------------
// CrossCausalAttentionBlock on MI355X (gfx950)
// B=8, T=1024 (V=4 blocks of 256), C=512, NH=8, hd=64
// R11: prep rebuilt — wconv 64x64 vectorized tiles (1/4 blocks, f32x4 loads,
//      bf16x8 128B-segment stores); LN gather h-pair blocks (128B-dense read
//      segments). Split launches so LDS sizes don't couple. Rest = R10.
// ---------------------------------------------------------------------------

typedef __bf16 bf16;
typedef __bf16 bf16x8 __attribute__((ext_vector_type(8)));
typedef __bf16 bf16x4 __attribute__((ext_vector_type(4)));
typedef float  f32x4  __attribute__((ext_vector_type(4)));

__device__ __forceinline__ void gload_lds16(const void* g, void* l) {
  __builtin_amdgcn_global_load_lds(
      (__attribute__((address_space(1))) void*)(g),
      (__attribute__((address_space(3))) void*)(l), 16, 0, 0);
}

// ---------------------------------------------------------------------------
// Kernel 1a: weight converts fp32[K][N] -> bf16[N][K], 64x64 tiles, 768 blocks.
// Loads f32x4 (4x256B segments/instr); LDS [64][65] f32 (<=2-way banks both
// phases); stores bf16x8 (8x128B segments/instr).
// ---------------------------------------------------------------------------
__global__ __launch_bounds__(256)
void prep_w_k(const float* __restrict__ Wq, const float* __restrict__ Wkv,
              const float* __restrict__ Wo, const float* __restrict__ Wfc,
              const float* __restrict__ Wpr,
              bf16* __restrict__ WqT, bf16* __restrict__ WkvT,
              bf16* __restrict__ WoT, bf16* __restrict__ WfcT,
              bf16* __restrict__ WprT)
{
  __shared__ float tile[64 * 65]; // 16.6 KB
  const int t = blockIdx.x;
  const int tid = threadIdx.x;
  const float* W; bf16* Wt; int K, N, nx, tl;
  if (t < 64)        { W = Wq;  Wt = WqT;  K = 512;  N = 512;  nx = 8;  tl = t; }
  else if (t < 192)  { W = Wkv; Wt = WkvT; K = 512;  N = 1024; nx = 16; tl = t - 64; }
  else if (t < 256)  { W = Wo;  Wt = WoT;  K = 512;  N = 512;  nx = 8;  tl = t - 192; }
  else if (t < 512)  { W = Wfc; Wt = WfcT; K = 512;  N = 2048; nx = 32; tl = t - 256; }
  else               { W = Wpr; Wt = WprT; K = 2048; N = 512;  nx = 8;  tl = t - 512; }
  const int bx = tl % nx, by = tl / nx;
  const int n0 = bx << 6, k0 = by << 6;

  // load phase: thread (xl=tid&15 col-quad, yl=tid>>4 row), 4 rows apart
  const int xl = tid & 15, yl = tid >> 4;
#pragma unroll
  for (int r = 0; r < 4; ++r) {
    const int row = yl + r * 16;
    const f32x4 vv = *(const f32x4*)&W[(size_t)(k0 + row) * N + n0 + xl * 4];
#pragma unroll
    for (int e = 0; e < 4; ++e)
      tile[row * 65 + xl * 4 + e] = vv[e];
  }
  __syncthreads();
  // store phase: thread (xk=tid&7 k-octet, nl=tid>>3 n-row), 2 passes
  const int xk = tid & 7, nl = tid >> 3;
#pragma unroll
  for (int r2 = 0; r2 < 2; ++r2) {
    const int n = nl + r2 * 32;
    bf16x8 o;
#pragma unroll
    for (int e = 0; e < 8; ++e)
      o[e] = (bf16)tile[(xk * 8 + e) * 65 + n];
    *(bf16x8*)&Wt[(size_t)(n0 + n) * K + k0 + xk * 8] = o;
  }
}

// ---------------------------------------------------------------------------
// Kernel 1b: gather [v,b,c,h,w] -> [b,t,c] + LN1, h-pair blocks.
// Block = (sel, v, b, hp) covering 32 tokens (2 h-rows); thread (q8=tid&7,
// chb=tid>>3) owns 16 consecutive channels x 4 tokens. Reads: 8x128B dense
// segments per wave-instr. Stats: shfl_xor(8/16/32) + 1KB cross-wave LDS.
// ---------------------------------------------------------------------------
__global__ __launch_bounds__(256)
void prep_ln_k(const float* __restrict__ xi, const float* __restrict__ xj,
               const float* __restrict__ xc,
               const float* __restrict__ g, const float* __restrict__ bb,
               bf16* __restrict__ qs, bf16* __restrict__ kvs,
               bf16* __restrict__ csb)
{
  __shared__ __align__(16) float red[4][64];
  const int tid = threadIdx.x;
  const int u = blockIdx.x;
  const int sel = u >> 8, bid = u & 255;
  const int hp = bid & 7, b = (bid >> 3) & 7, v = bid >> 6;
  const float* src = (sel == 0) ? xi : ((sel == 1) ? xj : xc);
  const size_t base = ((size_t)(v * 8 + b) * 512) * 256 + hp * 32;
  const int q8 = tid & 7, chb = tid >> 3;
  const int wid = tid >> 6, lc = (tid >> 3) & 7;
  const int cb = chb << 4; // 16 consecutive channels

  // gamma/beta: 4 f32x4 each
  float gr[16], br[16];
#pragma unroll
  for (int p = 0; p < 4; ++p) {
    *(f32x4*)&gr[p * 4] = *(const f32x4*)&g[cb + p * 4];
    *(f32x4*)&br[p * 4] = *(const f32x4*)&bb[cb + p * 4];
  }
  // 16 ch x 4 tokens in registers (128B-dense wave segments)
  f32x4 x[16];
#pragma unroll
  for (int k = 0; k < 16; ++k)
    x[k] = *(const f32x4*)&src[base + (size_t)(cb + k) * 256 + q8 * 4];

  // per-token partial stats over this thread's 16 channels
  float s[4] = {0.f, 0.f, 0.f, 0.f}, ss[4] = {0.f, 0.f, 0.f, 0.f};
#pragma unroll
  for (int k = 0; k < 16; ++k)
#pragma unroll
    for (int i = 0; i < 4; ++i) {
      s[i] += x[k][i];
      ss[i] += x[k][i] * x[k][i];
    }
  // reduce across the 8 chb-lanes of this wave (offsets preserve q8)
#pragma unroll
  for (int off = 8; off < 64; off <<= 1)
#pragma unroll
    for (int i = 0; i < 4; ++i) {
      s[i] += __shfl_xor(s[i], off);
      ss[i] += __shfl_xor(ss[i], off);
    }
  // cross-wave combine: red[w][q8*4+i] = s, red[w][32+q8*4+i] = ss
  if (lc < 4)      red[wid][q8 * 4 + lc]      = s[lc];
  else             red[wid][32 + q8 * 4 + (lc - 4)] = ss[lc - 4];
  __syncthreads();
  f32x4 st = {0.f, 0.f, 0.f, 0.f}, sst = {0.f, 0.f, 0.f, 0.f};
#pragma unroll
  for (int w = 0; w < 4; ++w) {
    st  += *(const f32x4*)&red[w][q8 * 4];
    sst += *(const f32x4*)&red[w][32 + q8 * 4];
  }
  float mu[4], rs[4];
#pragma unroll
  for (int i = 0; i < 4; ++i) {
    mu[i] = st[i] * (1.f / 512.f);
    rs[i] = rsqrtf(sst[i] * (1.f / 512.f) - mu[i] * mu[i] + 1e-5f);
  }
  // normalize + store (2 bf16x8 per token)
  bf16* dstb = (sel == 0) ? qs : ((sel == 1) ? kvs : csb);
  const int tkb = v * 256 + hp * 32 + q8 * 4;
#pragma unroll
  for (int i = 0; i < 4; ++i) {
    const size_t orow = ((size_t)b * 1024 + tkb + i) * 512 + cb;
    bf16x8 o0, o1;
#pragma unroll
    for (int k = 0; k < 8; ++k) {
      o0[k] = (bf16)((x[k][i] - mu[i]) * rs[i] * gr[k] + br[k]);
      o1[k] = (bf16)((x[k + 8][i] - mu[i]) * rs[i] * gr[k + 8] + br[k + 8]);
    }
    *(bf16x8*)&dstb[orow]     = o0;
    *(bf16x8*)&dstb[orow + 8] = o1;
  }
}

// ---------------------------------------------------------------------------
// Kernel 3: row LayerNorm(ln2) on cs bf16[8192][512] -> hcs bf16. 1 wave/row.
// ---------------------------------------------------------------------------
__global__ __launch_bounds__(256)
void ln2_k(const bf16* __restrict__ cs, const float* __restrict__ g,
           const float* __restrict__ bb, bf16* __restrict__ hcs)
{
  const int tid = threadIdx.x, wid = tid >> 6, lane = tid & 63;
  const int row = blockIdx.x * 4 + wid;
  const bf16x8 v8 = *(const bf16x8*)&cs[(size_t)row * 512 + lane * 8];
  float v[8];
#pragma unroll
  for (int k = 0; k < 8; ++k) v[k] = (float)v8[k];
  float s = 0.f, ss = 0.f;
#pragma unroll
  for (int k = 0; k < 8; ++k) { s += v[k]; ss += v[k] * v[k]; }
#pragma unroll
  for (int off = 1; off < 64; off <<= 1) {
    s += __shfl_xor(s, off);
    ss += __shfl_xor(ss, off);
  }
  const float mu = s * (1.f / 512.f);
  const float rstd = rsqrtf(ss * (1.f / 512.f) - mu * mu + 1e-5f);
  bf16x8 o;
#pragma unroll
  for (int k = 0; k < 8; ++k) {
    int ch = lane * 8 + k;
    o[k] = (bf16)((v[k] - mu) * rstd * g[ch] + bb[ch]);
  }
  *(bf16x8*)&hcs[(size_t)row * 512 + lane * 8] = o;
}

// ---------------------------------------------------------------------------
// Kernel 4: FC GEMM (M=8192, N=2048, K=512), 2-phase dbuf, GELU epilogue
// staged through padded LDS (stride 132) for full-line coalesced stores.
// ---------------------------------------------------------------------------
__global__ __launch_bounds__(256)
void gemm_fc_k(const bf16* __restrict__ A, const bf16* __restrict__ Bt,
               const float* __restrict__ bias, bf16* __restrict__ fo)
{
  const int K = 512;
  __shared__ __align__(16) char smem[34816];
  bf16* As = (bf16*)smem;            // [2][4096]
  bf16* Bs = (bf16*)(smem + 16384);  // [2][4096]
  const int tid = threadIdx.x;
  const int wid = tid >> 6, lane = tid & 63;
  const int wr = wid >> 1, wc = wid & 1;
  const int ml = lane & 15, kg = (lane >> 4) << 3;
  const int m0 = blockIdx.x * 128, n0 = blockIdx.y * 128;

  const int e0 = wid * 512 + lane * 8;
  const int r0 = e0 >> 5, c0 = e0 & 31;
  const int e1 = e0 + 2048;
  const int r1 = e1 >> 5, c1 = e1 & 31;

  const bf16* Ag = A + (size_t)m0 * K;
  const bf16* Bg = Bt + (size_t)n0 * K;

  f32x4 acc[4][4] = {};

  gload_lds16(Ag + (size_t)r0 * K + c0, As + wid * 512);
  gload_lds16(Ag + (size_t)r1 * K + c1, As + 2048 + wid * 512);
  gload_lds16(Bg + (size_t)r0 * K + c0, Bs + wid * 512);
  gload_lds16(Bg + (size_t)r1 * K + c1, Bs + 2048 + wid * 512);

  int cur = 0;
  for (int k0 = 0; k0 < K; k0 += 32) {
    __syncthreads();
    if (k0 + 32 < K) {
      const int nb = cur ^ 1, kn = k0 + 32;
      gload_lds16(Ag + (size_t)r0 * K + kn + c0, As + nb * 4096 + wid * 512);
      gload_lds16(Ag + (size_t)r1 * K + kn + c1, As + nb * 4096 + 2048 + wid * 512);
      gload_lds16(Bg + (size_t)r0 * K + kn + c0, Bs + nb * 4096 + wid * 512);
      gload_lds16(Bg + (size_t)r1 * K + kn + c1, Bs + nb * 4096 + 2048 + wid * 512);
    }
    bf16x8 af[4], bfr[4];
#pragma unroll
    for (int mf = 0; mf < 4; ++mf)
      af[mf] = *(const bf16x8*)&As[cur * 4096 + (wr * 64 + mf * 16 + ml) * 32 + kg];
#pragma unroll
    for (int nf = 0; nf < 4; ++nf)
      bfr[nf] = *(const bf16x8*)&Bs[cur * 4096 + (wc * 64 + nf * 16 + ml) * 32 + kg];
#pragma unroll
    for (int mf = 0; mf < 4; ++mf)
#pragma unroll
      for (int nf = 0; nf < 4; ++nf)
        acc[mf][nf] = __builtin_amdgcn_mfma_f32_16x16x32_bf16(
            af[mf], bfr[nf], acc[mf][nf], 0, 0, 0);
    cur ^= 1;
  }

  __syncthreads();
  bf16* OT = (bf16*)smem; // [128][132]
  const int jrow0 = (lane >> 4) << 2;
#pragma unroll
  for (int nf = 0; nf < 4; ++nf) {
    const float bv = bias[n0 + wc * 64 + nf * 16 + ml];
#pragma unroll
    for (int mf = 0; mf < 4; ++mf)
#pragma unroll
      for (int j = 0; j < 4; ++j) {
        float x = acc[mf][nf][j] + bv;
        float u = 0.7978845608f * (x + 0.044715f * x * x * x);
        float e = __expf(2.f * u);
        float th = 1.f - 2.f / (e + 1.f);
        OT[(wr * 64 + mf * 16 + jrow0 + j) * 132 + wc * 64 + nf * 16 + ml] =
            (bf16)(0.5f * x * (1.f + th));
      }
  }
  __syncthreads();
#pragma unroll
  for (int it = 0; it < 8; ++it) {
    const int idx = it * 256 + tid;
    const int cg = idx & 15, r = idx >> 4;
    *(bf16x8*)&fo[(size_t)(m0 + r) * 2048 + n0 + cg * 8] =
        *(const bf16x8*)&OT[r * 132 + cg * 8];
  }
}

// ---------------------------------------------------------------------------
// Kernel 4b: in-block split-K GEMM for N=512 stages (O, PR). BM=64, BN=128,
// grid (128,4) = 512 blocks = 2/CU. 512 threads = 2 K-half groups x 4 waves.
// ---------------------------------------------------------------------------
enum { EPI_O = 2, EPI_PR = 4 };

template <int EPI>
__global__ __launch_bounds__(512)
void gemmsk_k(const bf16* __restrict__ A, const bf16* __restrict__ Bt,
              const float* __restrict__ bias, const bf16* res,
              void* out0, int K)
{
  __shared__ __align__(16) char smem[49152];
  bf16*  AS = (bf16*)smem;            // [2 dbuf][2 half][2048] = 16 KB
  bf16*  BS = (bf16*)(smem + 16384);  // [2 dbuf][2 half][4096] = 32 KB
  float* CF = (float*)smem;           // f32[64][128] = 32 KB overlay

  const int tid = threadIdx.x;
  const int wid = tid >> 6, lane = tid & 63;
  const int half = wid >> 2, w2 = wid & 3;
  const int wr = w2 >> 1, wc = w2 & 1;
  const int ml = lane & 15, kg = (lane >> 4) << 3;
  const int m0 = blockIdx.x * 64, n0 = blockIdx.y * 128;
  const int Kh = K >> 1;

  const int eA = w2 * 512 + lane * 8;
  const int rA = eA >> 5, cA = eA & 31;
  const int eB0 = (w2 * 2) * 512 + lane * 8;
  const int rB0 = eB0 >> 5, cB0 = eB0 & 31;
  const int eB1 = eB0 + 512;
  const int rB1 = eB1 >> 5, cB1 = eB1 & 31;

  const bf16* Ag = A + (size_t)m0 * K + half * Kh;
  const bf16* Bg = Bt + (size_t)n0 * K + half * Kh;

  f32x4 acc[2][4] = {};

  gload_lds16(Ag + (size_t)rA * K + cA, AS + half * 2048 + w2 * 512);
  gload_lds16(Bg + (size_t)rB0 * K + cB0, BS + half * 4096 + (w2 * 2) * 512);
  gload_lds16(Bg + (size_t)rB1 * K + cB1, BS + half * 4096 + (w2 * 2 + 1) * 512);

  int cur = 0;
  for (int k0 = 0; k0 < Kh; k0 += 32) {
    __syncthreads();
    if (k0 + 32 < Kh) {
      const int kn = k0 + 32, nb = cur ^ 1;
      gload_lds16(Ag + (size_t)rA * K + kn + cA,
                  AS + nb * 4096 + half * 2048 + w2 * 512);
      gload_lds16(Bg + (size_t)rB0 * K + kn + cB0,
                  BS + nb * 8192 + half * 4096 + (w2 * 2) * 512);
      gload_lds16(Bg + (size_t)rB1 * K + kn + cB1,
                  BS + nb * 8192 + half * 4096 + (w2 * 2 + 1) * 512);
    }
    const bf16* Ac = AS + cur * 4096 + half * 2048;
    const bf16* Bc = BS + cur * 8192 + half * 4096;
    bf16x8 af[2], bfr[4];
#pragma unroll
    for (int mf = 0; mf < 2; ++mf)
      af[mf] = *(const bf16x8*)&Ac[(wr * 32 + mf * 16 + ml) * 32 + kg];
#pragma unroll
    for (int nf = 0; nf < 4; ++nf)
      bfr[nf] = *(const bf16x8*)&Bc[(wc * 64 + nf * 16 + ml) * 32 + kg];
#pragma unroll
    for (int mf = 0; mf < 2; ++mf)
#pragma unroll
      for (int nf = 0; nf < 4; ++nf)
        acc[mf][nf] = __builtin_amdgcn_mfma_f32_16x16x32_bf16(
            af[mf], bfr[nf], acc[mf][nf], 0, 0, 0);
    cur ^= 1;
  }

  const int jrow0 = (lane >> 4) << 2;
  __syncthreads(); // staging dead; CF may overlay AS/BS
  if (half == 0) {
#pragma unroll
    for (int mf = 0; mf < 2; ++mf)
#pragma unroll
      for (int nf = 0; nf < 4; ++nf)
#pragma unroll
        for (int j = 0; j < 4; ++j)
          CF[(wr * 32 + mf * 16 + jrow0 + j) * 128 + wc * 64 + nf * 16 + ml] =
              acc[mf][nf][j];
  }
  __syncthreads();
  if (half == 1) {
#pragma unroll
    for (int nf = 0; nf < 4; ++nf) {
      const int n = n0 + wc * 64 + nf * 16 + ml;
      const float bv = bias[n];
#pragma unroll
      for (int mf = 0; mf < 2; ++mf) {
        const int mbase = m0 + wr * 32 + mf * 16 + jrow0;
        float v4[4];
#pragma unroll
        for (int j = 0; j < 4; ++j)
          v4[j] = acc[mf][nf][j] +
                  CF[(wr * 32 + mf * 16 + jrow0 + j) * 128 + wc * 64 + nf * 16 + ml];
        if constexpr (EPI == EPI_O) {
          bf16* cs = (bf16*)out0; // in-place with res
#pragma unroll
          for (int j = 0; j < 4; ++j) {
            const size_t idx = (size_t)(mbase + j) * 512 + n;
            cs[idx] = (bf16)(v4[j] + bv + (float)res[idx]);
          }
        } else {
          float* out = (float*)out0;
          const int b = mbase >> 10, t = mbase & 1023;
          const int v = t >> 8, hhh = (t >> 4) & 15, w0 = t & 15;
          f32x4 o;
#pragma unroll
          for (int j = 0; j < 4; ++j)
            o[j] = v4[j] + bv + (float)res[(size_t)(mbase + j) * 512 + n];
          *(f32x4*)&out[(((size_t)v * 8 + b) * 512 + n) * 256 + hhh * 16 + w0] = o;
        }
      }
    }
  }
}

// ---------------------------------------------------------------------------
// Kernel 4c: merged Q + KV projection GEMM, 2-phase dbuf, LDS-staged stores.
// Grid (64, 12): ybl 0-3 Q, 4-7 K, 8-11 V(transposed).
// ---------------------------------------------------------------------------
__global__ __launch_bounds__(256)
void gemm_qkv_k(const bf16* __restrict__ Aq, const bf16* __restrict__ Akv,
                const bf16* __restrict__ WqT, const bf16* __restrict__ WkvT,
                const float* __restrict__ bq, const float* __restrict__ bkv,
                bf16* __restrict__ q_buf, bf16* __restrict__ k_buf,
                bf16* __restrict__ v_t)
{
  const int K = 512;
  __shared__ __align__(16) char smem[34816];
  bf16* As = (bf16*)smem;
  bf16* Bs = (bf16*)(smem + 16384);
  const int tid = threadIdx.x;
  const int wid = tid >> 6, lane = tid & 63;
  const int wr = wid >> 1, wc = wid & 1;
  const int ml = lane & 15, kg = (lane >> 4) << 3;
  const int ybl = blockIdx.y;
  const bool isq = ybl < 4;
  const bf16* A     = isq ? Aq  : Akv;
  const bf16* Bt    = isq ? WqT : WkvT;
  const float* bias = isq ? bq : bkv;
  const int n0 = isq ? (ybl << 7) : ((ybl - 4) << 7);
  const int m0 = blockIdx.x * 128;

  const int e0 = wid * 512 + lane * 8;
  const int r0 = e0 >> 5, c0 = e0 & 31;
  const int e1 = e0 + 2048;
  const int r1 = e1 >> 5, c1 = e1 & 31;

  const bf16* Ag = A + (size_t)m0 * K;
  const bf16* Bg = Bt + (size_t)n0 * K;

  f32x4 acc[4][4] = {};

  gload_lds16(Ag + (size_t)r0 * K + c0, As + wid * 512);
  gload_lds16(Ag + (size_t)r1 * K + c1, As + 2048 + wid * 512);
  gload_lds16(Bg + (size_t)r0 * K + c0, Bs + wid * 512);
  gload_lds16(Bg + (size_t)r1 * K + c1, Bs + 2048 + wid * 512);

  int cur = 0;
  for (int k0 = 0; k0 < K; k0 += 32) {
    __syncthreads();
    if (k0 + 32 < K) {
      const int nb = cur ^ 1, kn = k0 + 32;
      gload_lds16(Ag + (size_t)r0 * K + kn + c0, As + nb * 4096 + wid * 512);
      gload_lds16(Ag + (size_t)r1 * K + kn + c1, As + nb * 4096 + 2048 + wid * 512);
      gload_lds16(Bg + (size_t)r0 * K + kn + c0, Bs + nb * 4096 + wid * 512);
      gload_lds16(Bg + (size_t)r1 * K + kn + c1, Bs + nb * 4096 + 2048 + wid * 512);
    }
    bf16x8 af[4], bfr[4];
#pragma unroll
    for (int mf = 0; mf < 4; ++mf)
      af[mf] = *(const bf16x8*)&As[cur * 4096 + (wr * 64 + mf * 16 + ml) * 32 + kg];
#pragma unroll
    for (int nf = 0; nf < 4; ++nf)
      bfr[nf] = *(const bf16x8*)&Bs[cur * 4096 + (wc * 64 + nf * 16 + ml) * 32 + kg];
#pragma unroll
    for (int mf = 0; mf < 4; ++mf)
#pragma unroll
      for (int nf = 0; nf < 4; ++nf)
        acc[mf][nf] = __builtin_amdgcn_mfma_f32_16x16x32_bf16(
            af[mf], bfr[nf], acc[mf][nf], 0, 0, 0);
    cur ^= 1;
  }

  __syncthreads();
  bf16* OT = (bf16*)smem; // [128][132] padded
  const int jrow0 = (lane >> 4) << 2;
  const int b = m0 >> 10, t0 = m0 & 1023;
  if (ybl < 8) { // Q or K: stage row-major (row=m, col=n)
#pragma unroll
    for (int nf = 0; nf < 4; ++nf) {
      const float bv = bias[n0 + wc * 64 + nf * 16 + ml];
#pragma unroll
      for (int mf = 0; mf < 4; ++mf)
#pragma unroll
        for (int j = 0; j < 4; ++j)
          OT[(wr * 64 + mf * 16 + jrow0 + j) * 132 + wc * 64 + nf * 16 + ml] =
              (bf16)(acc[mf][nf][j] + bv);
    }
    __syncthreads();
    bf16* dst = isq ? q_buf : k_buf;
    const int h0 = n0 >> 6;
#pragma unroll
    for (int it = 0; it < 8; ++it) {
      const int idx = it * 256 + tid;
      const int dg = idx & 7, r = (idx >> 3) & 127, hl = idx >> 10;
      *(bf16x8*)&dst[(((size_t)b * 8 + h0 + hl) * 1024 + t0 + r) * 64 + dg * 8] =
          *(const bf16x8*)&OT[r * 132 + hl * 64 + dg * 8];
    }
  } else { // V: stage col-major for t-contiguous stores
#pragma unroll
    for (int nf = 0; nf < 4; ++nf) {
      const float bv = bias[n0 + wc * 64 + nf * 16 + ml];
#pragma unroll
      for (int mf = 0; mf < 4; ++mf) {
        bf16x4 o;
#pragma unroll
        for (int j = 0; j < 4; ++j) o[j] = (bf16)(acc[mf][nf][j] + bv);
        *(bf16x4*)&OT[(wc * 64 + nf * 16 + ml) * 132 + wr * 64 + mf * 16 + jrow0] = o;
      }
    }
    __syncthreads();
    const int h0 = (n0 - 512) >> 6;
#pragma unroll
    for (int it = 0; it < 8; ++it) {
      const int idx = it * 256 + tid;
      const int og = idx & 15, c = idx >> 4;
      const int hl = c >> 6, d = c & 63;
      *(bf16x8*)&v_t[(((size_t)b * 8 + h0 + hl) * 64 + d) * 1024 + t0 + og * 8] =
          *(const bf16x8*)&OT[c * 132 + og * 8];
    }
  }
}

// ---------------------------------------------------------------------------
// Kernel 5: block-causal flash attention (+ T5 setprio, unchanged from R10).
// ---------------------------------------------------------------------------
__global__ __launch_bounds__(256)
void attn_k(const bf16* __restrict__ qb, const bf16* __restrict__ kb,
            const bf16* __restrict__ vt, bf16* __restrict__ y)
{
  __shared__ bf16 Ks[2][4096];
  __shared__ bf16 Vs[2][4096];
  __shared__ bf16 Ps[4][1024];
  const int tid = threadIdx.x, wid = tid >> 6, lane = tid & 63;
  const int L = blockIdx.x;
  const int xcd = L & 7, chunk = L >> 3;
  const int bh = xcd + ((chunk >> 4) << 3);
  const int qt = 15 - (chunk & 15);
  const int b = bh >> 3, h = bh & 7;
  const int t0 = qt << 6;
  const int ml = lane & 15, hi = lane >> 4, kg = hi << 3;

  const bf16* qrow = qb + ((size_t)bh * 1024 + t0 + wid * 16) * 64;
  bf16x8 aq[2];
  aq[0] = *(const bf16x8*)&qrow[ml * 64 + kg];
  aq[1] = *(const bf16x8*)&qrow[ml * 64 + 32 + kg];

  f32x4 accO[4] = {};
  float lsum[4] = {0.f, 0.f, 0.f, 0.f};

  const int nkt = ((qt >> 2) + 1) << 2;
  const bf16* kbase = kb + (size_t)bh * 1024 * 64;
  const bf16* vbase = vt + (size_t)bh * 64 * 1024;

  const int sr = (wid << 3) + (lane >> 3);
  const int sg = ((lane & 7) ^ ((lane >> 3) & 7)) << 3;
  bf16* pw = &Ps[wid][0];

  {
    gload_lds16(kbase + (size_t)sr * 64 + sg,          &Ks[0][wid * 512]);
    gload_lds16(kbase + (size_t)(sr + 32) * 64 + sg,   &Ks[0][2048 + wid * 512]);
    gload_lds16(vbase + (size_t)sr * 1024 + sg,        &Vs[0][wid * 512]);
    gload_lds16(vbase + (size_t)(sr + 32) * 1024 + sg, &Vs[0][2048 + wid * 512]);
  }

  int cur = 0;
  for (int kt = 0; kt < nkt; ++kt) {
    __syncthreads();
    if (kt + 1 < nkt) {
      const int tk0 = (kt + 1) << 6;
      const int nb = cur ^ 1;
      gload_lds16(kbase + (size_t)(tk0 + sr) * 64 + sg,        &Ks[nb][wid * 512]);
      gload_lds16(kbase + (size_t)(tk0 + sr + 32) * 64 + sg,   &Ks[nb][2048 + wid * 512]);
      gload_lds16(vbase + (size_t)sr * 1024 + tk0 + sg,        &Vs[nb][wid * 512]);
      gload_lds16(vbase + (size_t)(sr + 32) * 1024 + tk0 + sg, &Vs[nb][2048 + wid * 512]);
    }

    f32x4 sa[4] = {};
    __builtin_amdgcn_s_setprio(1);
#pragma unroll
    for (int nf = 0; nf < 4; ++nf) {
      const int row = nf * 16 + ml;
#pragma unroll
      for (int ks = 0; ks < 2; ++ks) {
        const int g = ((ks * 4 + hi) ^ (ml & 7)) << 3;
        bf16x8 bk = *(const bf16x8*)&Ks[cur][row * 64 + g];
        sa[nf] = __builtin_amdgcn_mfma_f32_16x16x32_bf16(aq[ks], bk, sa[nf], 0, 0, 0);
      }
    }
    __builtin_amdgcn_s_setprio(0);

#pragma unroll
    for (int nf = 0; nf < 4; ++nf) {
      const int gp0 = nf * 2 + (ml >> 3);
#pragma unroll
      for (int j = 0; j < 4; ++j) {
        const float p = __expf(sa[nf][j] * 0.125f);
        lsum[j] += p;
        const int prow = (hi << 2) + j;
        pw[prow * 64 + ((gp0 ^ (prow & 7)) << 3) + (ml & 7)] = (bf16)p;
      }
    }

    __builtin_amdgcn_s_setprio(1);
#pragma unroll
    for (int ks = 0; ks < 2; ++ks) {
      const int g = ((ks * 4 + hi) ^ (ml & 7)) << 3;
      bf16x8 pa = *(const bf16x8*)&pw[ml * 64 + g];
#pragma unroll
      for (int df = 0; df < 4; ++df) {
        bf16x8 bv = *(const bf16x8*)&Vs[cur][(df * 16 + ml) * 64 + g];
        accO[df] = __builtin_amdgcn_mfma_f32_16x16x32_bf16(pa, bv, accO[df], 0, 0, 0);
      }
    }
    __builtin_amdgcn_s_setprio(0);
    cur ^= 1;
  }

  float inv[4];
#pragma unroll
  for (int j = 0; j < 4; ++j) {
    float s = lsum[j];
#pragma unroll
    for (int off = 1; off < 16; off <<= 1) s += __shfl_xor(s, off);
    inv[j] = 1.f / s;
  }
#pragma unroll
  for (int df = 0; df < 4; ++df)
#pragma unroll
    for (int j = 0; j < 4; ++j) {
      const int t = t0 + wid * 16 + (hi << 2) + j;
      const int c = h * 64 + df * 16 + ml;
      y[((size_t)b * 1024 + t) * 512 + c] = (bf16)(accO[df][j] * inv[j]);
    }
}

// ---------------------------------------------------------------------------
extern "C" void kernel_launch(void* const* d_in, const int* in_sizes, int n_in,
                              void* d_out, int out_size, void* d_ws, size_t ws_size,
                              hipStream_t stream)
{
  const float* xi    = (const float*)d_in[0];
  const float* xc    = (const float*)d_in[1];
  const float* xj    = (const float*)d_in[2];
  const float* ln1_g = (const float*)d_in[3];
  const float* ln1_b = (const float*)d_in[4];
  const float* ln2_g = (const float*)d_in[5];
  const float* ln2_b = (const float*)d_in[6];
  const float* Wq    = (const float*)d_in[7];
  const float* bq    = (const float*)d_in[8];
  const float* Wkv   = (const float*)d_in[9];
  const float* bkv   = (const float*)d_in[10];
  const float* Wo    = (const float*)d_in[11];
  const float* bo    = (const float*)d_in[12];
  const float* Wfc   = (const float*)d_in[13];
  const float* bfc   = (const float*)d_in[14];
  const float* Wpr   = (const float*)d_in[15];
  const float* bpr   = (const float*)d_in[16];

  char* ws = (char*)d_ws;
  const size_t MB = 1ull << 20;
  bf16*  qs    = (bf16*)(ws + 0);                  // 8 MB
  bf16*  kvs   = (bf16*)(ws + 8 * MB);             // 8 MB
  bf16*  csb   = (bf16*)(ws + 16 * MB);            // 8 MB (bf16 residual)
  bf16*  WqT   = (bf16*)(ws + 32 * MB);
  bf16*  WkvT  = (bf16*)(ws + 32 * MB + 512 * 1024);
  bf16*  WoT   = (bf16*)(ws + 33 * MB + 512 * 1024);
  bf16*  WfcT  = (bf16*)(ws + 34 * MB);
  bf16*  WprT  = (bf16*)(ws + 36 * MB);
  bf16*  q_buf = (bf16*)(ws + 38 * MB);
  bf16*  k_buf = (bf16*)(ws + 46 * MB);
  bf16*  v_t   = (bf16*)(ws + 54 * MB);
  bf16*  yb    = (bf16*)(ws + 0);                  // reuse qs
  bf16*  hcs   = (bf16*)(ws + 8 * MB);             // reuse kvs
  bf16*  fcact = (bf16*)(ws + 38 * MB);            // reuse q/k/v

  prep_w_k<<<dim3(768), 256, 0, stream>>>(Wq, Wkv, Wo, Wfc, Wpr,
                                          WqT, WkvT, WoT, WfcT, WprT);
  prep_ln_k<<<dim3(768), 256, 0, stream>>>(xi, xj, xc, ln1_g, ln1_b,
                                           qs, kvs, csb);

  gemm_qkv_k<<<dim3(64, 12), 256, 0, stream>>>(qs, kvs, WqT, WkvT, bq, bkv,
                                               q_buf, k_buf, v_t);

  attn_k<<<dim3(1024), 256, 0, stream>>>(q_buf, k_buf, v_t, yb);

  gemmsk_k<EPI_O><<<dim3(128, 4), 512, 0, stream>>>(yb, WoT, bo, csb,
                                                    (void*)csb, 512);

  ln2_k<<<dim3(2048), 256, 0, stream>>>(csb, ln2_g, ln2_b, hcs);

  gemm_fc_k<<<dim3(64, 16), 256, 0, stream>>>(hcs, WfcT, bfc, fcact);

  gemmsk_k<EPI_PR><<<dim3(128, 4), 512, 0, stream>>>(fcact, WprT, bpr, csb,
                                                     d_out, 2048);

  (void)in_sizes; (void)n_in; (void)out_size; (void)ws_size;
}

// Round 12
// 155.225 us; speedup vs baseline: 1.1768x; 1.0475x over previous
//
#include <hip/hip_runtime.h>
#include <hip/hip_bf16.h>
#include <math.h>

// ---------------------------------------------------------------------------
// CrossCausalAttentionBlock on MI355X (gfx950)
// B=8, T=1024 (V=4 blocks of 256), C=512, NH=8, hd=64
// R12: attn QBLK 128 (8 waves, grid 512) — tile-visits halve (160->80/bh),
//      staging+barrier overhead halves; prep re-merged (one launch).
// ---------------------------------------------------------------------------

typedef __bf16 bf16;
typedef __bf16 bf16x8 __attribute__((ext_vector_type(8)));
typedef __bf16 bf16x4 __attribute__((ext_vector_type(4)));
typedef float  f32x4  __attribute__((ext_vector_type(4)));

__device__ __forceinline__ void gload_lds16(const void* g, void* l) {
  __builtin_amdgcn_global_load_lds(
      (__attribute__((address_space(1))) void*)(g),
      (__attribute__((address_space(3))) void*)(l), 16, 0, 0);
}

// ---------------------------------------------------------------------------
// Kernel 1: prep. Blocks 0..767: weight convert 64x64 tiles. 768..1535:
// gather+LN1 h-pair blocks (register-resident, vector loads/stores).
// ---------------------------------------------------------------------------
__global__ __launch_bounds__(256)
void prep_k(const float* __restrict__ Wq, const float* __restrict__ Wkv,
            const float* __restrict__ Wo, const float* __restrict__ Wfc,
            const float* __restrict__ Wpr,
            bf16* __restrict__ WqT, bf16* __restrict__ WkvT,
            bf16* __restrict__ WoT, bf16* __restrict__ WfcT,
            bf16* __restrict__ WprT,
            const float* __restrict__ xi, const float* __restrict__ xj,
            const float* __restrict__ xc,
            const float* __restrict__ g, const float* __restrict__ bb,
            bf16* __restrict__ qs, bf16* __restrict__ kvs,
            bf16* __restrict__ csb)
{
  __shared__ float tile[64 * 65]; // 16.6 KB (wconv half)
  __shared__ float red[4][64];    // 1 KB (LN half)
  const int t = blockIdx.x;
  const int tid = threadIdx.x;
  if (t < 768) { // ---- weight transpose-convert, 64x64 tiles
    const float* W; bf16* Wt; int K, N, nx, tl;
    if (t < 64)        { W = Wq;  Wt = WqT;  K = 512;  N = 512;  nx = 8;  tl = t; }
    else if (t < 192)  { W = Wkv; Wt = WkvT; K = 512;  N = 1024; nx = 16; tl = t - 64; }
    else if (t < 256)  { W = Wo;  Wt = WoT;  K = 512;  N = 512;  nx = 8;  tl = t - 192; }
    else if (t < 512)  { W = Wfc; Wt = WfcT; K = 512;  N = 2048; nx = 32; tl = t - 256; }
    else               { W = Wpr; Wt = WprT; K = 2048; N = 512;  nx = 8;  tl = t - 512; }
    const int bx = tl % nx, by = tl / nx;
    const int n0 = bx << 6, k0 = by << 6;
    const int xl = tid & 15, yl = tid >> 4;
#pragma unroll
    for (int r = 0; r < 4; ++r) {
      const int row = yl + r * 16;
      const f32x4 vv = *(const f32x4*)&W[(size_t)(k0 + row) * N + n0 + xl * 4];
#pragma unroll
      for (int e = 0; e < 4; ++e)
        tile[row * 65 + xl * 4 + e] = vv[e];
    }
    __syncthreads();
    const int xk = tid & 7, nl = tid >> 3;
#pragma unroll
    for (int r2 = 0; r2 < 2; ++r2) {
      const int n = nl + r2 * 32;
      bf16x8 o;
#pragma unroll
      for (int e = 0; e < 8; ++e)
        o[e] = (bf16)tile[(xk * 8 + e) * 65 + n];
      *(bf16x8*)&Wt[(size_t)(n0 + n) * K + k0 + xk * 8] = o;
    }
    return;
  }
  // ---- gather [v,b,c,h,w] -> [b,t,c] + LN1
  const int u = t - 768;
  const int sel = u >> 8, bid = u & 255;
  const int hp = bid & 7, b = (bid >> 3) & 7, v = bid >> 6;
  const float* src = (sel == 0) ? xi : ((sel == 1) ? xj : xc);
  const size_t base = ((size_t)(v * 8 + b) * 512) * 256 + hp * 32;
  const int q8 = tid & 7, chb = tid >> 3;
  const int wid = tid >> 6, lc = (tid >> 3) & 7;
  const int cb = chb << 4;

  float gr[16], br[16];
#pragma unroll
  for (int p = 0; p < 4; ++p) {
    *(f32x4*)&gr[p * 4] = *(const f32x4*)&g[cb + p * 4];
    *(f32x4*)&br[p * 4] = *(const f32x4*)&bb[cb + p * 4];
  }
  f32x4 x[16];
#pragma unroll
  for (int k = 0; k < 16; ++k)
    x[k] = *(const f32x4*)&src[base + (size_t)(cb + k) * 256 + q8 * 4];

  float s[4] = {0.f, 0.f, 0.f, 0.f}, ss[4] = {0.f, 0.f, 0.f, 0.f};
#pragma unroll
  for (int k = 0; k < 16; ++k)
#pragma unroll
    for (int i = 0; i < 4; ++i) {
      s[i] += x[k][i];
      ss[i] += x[k][i] * x[k][i];
    }
#pragma unroll
  for (int off = 8; off < 64; off <<= 1)
#pragma unroll
    for (int i = 0; i < 4; ++i) {
      s[i] += __shfl_xor(s[i], off);
      ss[i] += __shfl_xor(ss[i], off);
    }
  if (lc < 4)      red[wid][q8 * 4 + lc]            = s[lc];
  else             red[wid][32 + q8 * 4 + (lc - 4)] = ss[lc - 4];
  __syncthreads();
  f32x4 st = {0.f, 0.f, 0.f, 0.f}, sst = {0.f, 0.f, 0.f, 0.f};
#pragma unroll
  for (int w = 0; w < 4; ++w) {
    st  += *(const f32x4*)&red[w][q8 * 4];
    sst += *(const f32x4*)&red[w][32 + q8 * 4];
  }
  float mu[4], rs[4];
#pragma unroll
  for (int i = 0; i < 4; ++i) {
    mu[i] = st[i] * (1.f / 512.f);
    rs[i] = rsqrtf(sst[i] * (1.f / 512.f) - mu[i] * mu[i] + 1e-5f);
  }
  bf16* dstb = (sel == 0) ? qs : ((sel == 1) ? kvs : csb);
  const int tkb = v * 256 + hp * 32 + q8 * 4;
#pragma unroll
  for (int i = 0; i < 4; ++i) {
    const size_t orow = ((size_t)b * 1024 + tkb + i) * 512 + cb;
    bf16x8 o0, o1;
#pragma unroll
    for (int k = 0; k < 8; ++k) {
      o0[k] = (bf16)((x[k][i] - mu[i]) * rs[i] * gr[k] + br[k]);
      o1[k] = (bf16)((x[k + 8][i] - mu[i]) * rs[i] * gr[k + 8] + br[k + 8]);
    }
    *(bf16x8*)&dstb[orow]     = o0;
    *(bf16x8*)&dstb[orow + 8] = o1;
  }
}

// ---------------------------------------------------------------------------
// Kernel 3: row LayerNorm(ln2) on cs bf16[8192][512] -> hcs bf16. 1 wave/row.
// ---------------------------------------------------------------------------
__global__ __launch_bounds__(256)
void ln2_k(const bf16* __restrict__ cs, const float* __restrict__ g,
           const float* __restrict__ bb, bf16* __restrict__ hcs)
{
  const int tid = threadIdx.x, wid = tid >> 6, lane = tid & 63;
  const int row = blockIdx.x * 4 + wid;
  const bf16x8 v8 = *(const bf16x8*)&cs[(size_t)row * 512 + lane * 8];
  float v[8];
#pragma unroll
  for (int k = 0; k < 8; ++k) v[k] = (float)v8[k];
  float s = 0.f, ss = 0.f;
#pragma unroll
  for (int k = 0; k < 8; ++k) { s += v[k]; ss += v[k] * v[k]; }
#pragma unroll
  for (int off = 1; off < 64; off <<= 1) {
    s += __shfl_xor(s, off);
    ss += __shfl_xor(ss, off);
  }
  const float mu = s * (1.f / 512.f);
  const float rstd = rsqrtf(ss * (1.f / 512.f) - mu * mu + 1e-5f);
  bf16x8 o;
#pragma unroll
  for (int k = 0; k < 8; ++k) {
    int ch = lane * 8 + k;
    o[k] = (bf16)((v[k] - mu) * rstd * g[ch] + bb[ch]);
  }
  *(bf16x8*)&hcs[(size_t)row * 512 + lane * 8] = o;
}

// ---------------------------------------------------------------------------
// Kernel 4: FC GEMM (M=8192, N=2048, K=512), 2-phase dbuf, GELU epilogue
// staged through padded LDS (stride 132) for full-line coalesced stores.
// ---------------------------------------------------------------------------
__global__ __launch_bounds__(256)
void gemm_fc_k(const bf16* __restrict__ A, const bf16* __restrict__ Bt,
               const float* __restrict__ bias, bf16* __restrict__ fo)
{
  const int K = 512;
  __shared__ __align__(16) char smem[34816];
  bf16* As = (bf16*)smem;            // [2][4096]
  bf16* Bs = (bf16*)(smem + 16384);  // [2][4096]
  const int tid = threadIdx.x;
  const int wid = tid >> 6, lane = tid & 63;
  const int wr = wid >> 1, wc = wid & 1;
  const int ml = lane & 15, kg = (lane >> 4) << 3;
  const int m0 = blockIdx.x * 128, n0 = blockIdx.y * 128;

  const int e0 = wid * 512 + lane * 8;
  const int r0 = e0 >> 5, c0 = e0 & 31;
  const int e1 = e0 + 2048;
  const int r1 = e1 >> 5, c1 = e1 & 31;

  const bf16* Ag = A + (size_t)m0 * K;
  const bf16* Bg = Bt + (size_t)n0 * K;

  f32x4 acc[4][4] = {};

  gload_lds16(Ag + (size_t)r0 * K + c0, As + wid * 512);
  gload_lds16(Ag + (size_t)r1 * K + c1, As + 2048 + wid * 512);
  gload_lds16(Bg + (size_t)r0 * K + c0, Bs + wid * 512);
  gload_lds16(Bg + (size_t)r1 * K + c1, Bs + 2048 + wid * 512);

  int cur = 0;
  for (int k0 = 0; k0 < K; k0 += 32) {
    __syncthreads();
    if (k0 + 32 < K) {
      const int nb = cur ^ 1, kn = k0 + 32;
      gload_lds16(Ag + (size_t)r0 * K + kn + c0, As + nb * 4096 + wid * 512);
      gload_lds16(Ag + (size_t)r1 * K + kn + c1, As + nb * 4096 + 2048 + wid * 512);
      gload_lds16(Bg + (size_t)r0 * K + kn + c0, Bs + nb * 4096 + wid * 512);
      gload_lds16(Bg + (size_t)r1 * K + kn + c1, Bs + nb * 4096 + 2048 + wid * 512);
    }
    bf16x8 af[4], bfr[4];
#pragma unroll
    for (int mf = 0; mf < 4; ++mf)
      af[mf] = *(const bf16x8*)&As[cur * 4096 + (wr * 64 + mf * 16 + ml) * 32 + kg];
#pragma unroll
    for (int nf = 0; nf < 4; ++nf)
      bfr[nf] = *(const bf16x8*)&Bs[cur * 4096 + (wc * 64 + nf * 16 + ml) * 32 + kg];
#pragma unroll
    for (int mf = 0; mf < 4; ++mf)
#pragma unroll
      for (int nf = 0; nf < 4; ++nf)
        acc[mf][nf] = __builtin_amdgcn_mfma_f32_16x16x32_bf16(
            af[mf], bfr[nf], acc[mf][nf], 0, 0, 0);
    cur ^= 1;
  }

  __syncthreads();
  bf16* OT = (bf16*)smem; // [128][132]
  const int jrow0 = (lane >> 4) << 2;
#pragma unroll
  for (int nf = 0; nf < 4; ++nf) {
    const float bv = bias[n0 + wc * 64 + nf * 16 + ml];
#pragma unroll
    for (int mf = 0; mf < 4; ++mf)
#pragma unroll
      for (int j = 0; j < 4; ++j) {
        float x = acc[mf][nf][j] + bv;
        float u = 0.7978845608f * (x + 0.044715f * x * x * x);
        float e = __expf(2.f * u);
        float th = 1.f - 2.f / (e + 1.f);
        OT[(wr * 64 + mf * 16 + jrow0 + j) * 132 + wc * 64 + nf * 16 + ml] =
            (bf16)(0.5f * x * (1.f + th));
      }
  }
  __syncthreads();
#pragma unroll
  for (int it = 0; it < 8; ++it) {
    const int idx = it * 256 + tid;
    const int cg = idx & 15, r = idx >> 4;
    *(bf16x8*)&fo[(size_t)(m0 + r) * 2048 + n0 + cg * 8] =
        *(const bf16x8*)&OT[r * 132 + cg * 8];
  }
}

// ---------------------------------------------------------------------------
// Kernel 4b: in-block split-K GEMM for N=512 stages (O, PR). BM=64, BN=128,
// grid (128,4) = 512 blocks = 2/CU. 512 threads = 2 K-half groups x 4 waves.
// ---------------------------------------------------------------------------
enum { EPI_O = 2, EPI_PR = 4 };

template <int EPI>
__global__ __launch_bounds__(512)
void gemmsk_k(const bf16* __restrict__ A, const bf16* __restrict__ Bt,
              const float* __restrict__ bias, const bf16* res,
              void* out0, int K)
{
  __shared__ __align__(16) char smem[49152];
  bf16*  AS = (bf16*)smem;            // [2 dbuf][2 half][2048] = 16 KB
  bf16*  BS = (bf16*)(smem + 16384);  // [2 dbuf][2 half][4096] = 32 KB
  float* CF = (float*)smem;           // f32[64][128] = 32 KB overlay

  const int tid = threadIdx.x;
  const int wid = tid >> 6, lane = tid & 63;
  const int half = wid >> 2, w2 = wid & 3;
  const int wr = w2 >> 1, wc = w2 & 1;
  const int ml = lane & 15, kg = (lane >> 4) << 3;
  const int m0 = blockIdx.x * 64, n0 = blockIdx.y * 128;
  const int Kh = K >> 1;

  const int eA = w2 * 512 + lane * 8;
  const int rA = eA >> 5, cA = eA & 31;
  const int eB0 = (w2 * 2) * 512 + lane * 8;
  const int rB0 = eB0 >> 5, cB0 = eB0 & 31;
  const int eB1 = eB0 + 512;
  const int rB1 = eB1 >> 5, cB1 = eB1 & 31;

  const bf16* Ag = A + (size_t)m0 * K + half * Kh;
  const bf16* Bg = Bt + (size_t)n0 * K + half * Kh;

  f32x4 acc[2][4] = {};

  gload_lds16(Ag + (size_t)rA * K + cA, AS + half * 2048 + w2 * 512);
  gload_lds16(Bg + (size_t)rB0 * K + cB0, BS + half * 4096 + (w2 * 2) * 512);
  gload_lds16(Bg + (size_t)rB1 * K + cB1, BS + half * 4096 + (w2 * 2 + 1) * 512);

  int cur = 0;
  for (int k0 = 0; k0 < Kh; k0 += 32) {
    __syncthreads();
    if (k0 + 32 < Kh) {
      const int kn = k0 + 32, nb = cur ^ 1;
      gload_lds16(Ag + (size_t)rA * K + kn + cA,
                  AS + nb * 4096 + half * 2048 + w2 * 512);
      gload_lds16(Bg + (size_t)rB0 * K + kn + cB0,
                  BS + nb * 8192 + half * 4096 + (w2 * 2) * 512);
      gload_lds16(Bg + (size_t)rB1 * K + kn + cB1,
                  BS + nb * 8192 + half * 4096 + (w2 * 2 + 1) * 512);
    }
    const bf16* Ac = AS + cur * 4096 + half * 2048;
    const bf16* Bc = BS + cur * 8192 + half * 4096;
    bf16x8 af[2], bfr[4];
#pragma unroll
    for (int mf = 0; mf < 2; ++mf)
      af[mf] = *(const bf16x8*)&Ac[(wr * 32 + mf * 16 + ml) * 32 + kg];
#pragma unroll
    for (int nf = 0; nf < 4; ++nf)
      bfr[nf] = *(const bf16x8*)&Bc[(wc * 64 + nf * 16 + ml) * 32 + kg];
#pragma unroll
    for (int mf = 0; mf < 2; ++mf)
#pragma unroll
      for (int nf = 0; nf < 4; ++nf)
        acc[mf][nf] = __builtin_amdgcn_mfma_f32_16x16x32_bf16(
            af[mf], bfr[nf], acc[mf][nf], 0, 0, 0);
    cur ^= 1;
  }

  const int jrow0 = (lane >> 4) << 2;
  __syncthreads(); // staging dead; CF may overlay AS/BS
  if (half == 0) {
#pragma unroll
    for (int mf = 0; mf < 2; ++mf)
#pragma unroll
      for (int nf = 0; nf < 4; ++nf)
#pragma unroll
        for (int j = 0; j < 4; ++j)
          CF[(wr * 32 + mf * 16 + jrow0 + j) * 128 + wc * 64 + nf * 16 + ml] =
              acc[mf][nf][j];
  }
  __syncthreads();
  if (half == 1) {
#pragma unroll
    for (int nf = 0; nf < 4; ++nf) {
      const int n = n0 + wc * 64 + nf * 16 + ml;
      const float bv = bias[n];
#pragma unroll
      for (int mf = 0; mf < 2; ++mf) {
        const int mbase = m0 + wr * 32 + mf * 16 + jrow0;
        float v4[4];
#pragma unroll
        for (int j = 0; j < 4; ++j)
          v4[j] = acc[mf][nf][j] +
                  CF[(wr * 32 + mf * 16 + jrow0 + j) * 128 + wc * 64 + nf * 16 + ml];
        if constexpr (EPI == EPI_O) {
          bf16* cs = (bf16*)out0; // in-place with res
#pragma unroll
          for (int j = 0; j < 4; ++j) {
            const size_t idx = (size_t)(mbase + j) * 512 + n;
            cs[idx] = (bf16)(v4[j] + bv + (float)res[idx]);
          }
        } else {
          float* out = (float*)out0;
          const int b = mbase >> 10, t = mbase & 1023;
          const int v = t >> 8, hhh = (t >> 4) & 15, w0 = t & 15;
          f32x4 o;
#pragma unroll
          for (int j = 0; j < 4; ++j)
            o[j] = v4[j] + bv + (float)res[(size_t)(mbase + j) * 512 + n];
          *(f32x4*)&out[(((size_t)v * 8 + b) * 512 + n) * 256 + hhh * 16 + w0] = o;
        }
      }
    }
  }
}

// ---------------------------------------------------------------------------
// Kernel 4c: merged Q + KV projection GEMM, 2-phase dbuf, LDS-staged stores.
// Grid (64, 12): ybl 0-3 Q, 4-7 K, 8-11 V(transposed).
// ---------------------------------------------------------------------------
__global__ __launch_bounds__(256)
void gemm_qkv_k(const bf16* __restrict__ Aq, const bf16* __restrict__ Akv,
                const bf16* __restrict__ WqT, const bf16* __restrict__ WkvT,
                const float* __restrict__ bq, const float* __restrict__ bkv,
                bf16* __restrict__ q_buf, bf16* __restrict__ k_buf,
                bf16* __restrict__ v_t)
{
  const int K = 512;
  __shared__ __align__(16) char smem[34816];
  bf16* As = (bf16*)smem;
  bf16* Bs = (bf16*)(smem + 16384);
  const int tid = threadIdx.x;
  const int wid = tid >> 6, lane = tid & 63;
  const int wr = wid >> 1, wc = wid & 1;
  const int ml = lane & 15, kg = (lane >> 4) << 3;
  const int ybl = blockIdx.y;
  const bool isq = ybl < 4;
  const bf16* A     = isq ? Aq  : Akv;
  const bf16* Bt    = isq ? WqT : WkvT;
  const float* bias = isq ? bq : bkv;
  const int n0 = isq ? (ybl << 7) : ((ybl - 4) << 7);
  const int m0 = blockIdx.x * 128;

  const int e0 = wid * 512 + lane * 8;
  const int r0 = e0 >> 5, c0 = e0 & 31;
  const int e1 = e0 + 2048;
  const int r1 = e1 >> 5, c1 = e1 & 31;

  const bf16* Ag = A + (size_t)m0 * K;
  const bf16* Bg = Bt + (size_t)n0 * K;

  f32x4 acc[4][4] = {};

  gload_lds16(Ag + (size_t)r0 * K + c0, As + wid * 512);
  gload_lds16(Ag + (size_t)r1 * K + c1, As + 2048 + wid * 512);
  gload_lds16(Bg + (size_t)r0 * K + c0, Bs + wid * 512);
  gload_lds16(Bg + (size_t)r1 * K + c1, Bs + 2048 + wid * 512);

  int cur = 0;
  for (int k0 = 0; k0 < K; k0 += 32) {
    __syncthreads();
    if (k0 + 32 < K) {
      const int nb = cur ^ 1, kn = k0 + 32;
      gload_lds16(Ag + (size_t)r0 * K + kn + c0, As + nb * 4096 + wid * 512);
      gload_lds16(Ag + (size_t)r1 * K + kn + c1, As + nb * 4096 + 2048 + wid * 512);
      gload_lds16(Bg + (size_t)r0 * K + kn + c0, Bs + nb * 4096 + wid * 512);
      gload_lds16(Bg + (size_t)r1 * K + kn + c1, Bs + nb * 4096 + 2048 + wid * 512);
    }
    bf16x8 af[4], bfr[4];
#pragma unroll
    for (int mf = 0; mf < 4; ++mf)
      af[mf] = *(const bf16x8*)&As[cur * 4096 + (wr * 64 + mf * 16 + ml) * 32 + kg];
#pragma unroll
    for (int nf = 0; nf < 4; ++nf)
      bfr[nf] = *(const bf16x8*)&Bs[cur * 4096 + (wc * 64 + nf * 16 + ml) * 32 + kg];
#pragma unroll
    for (int mf = 0; mf < 4; ++mf)
#pragma unroll
      for (int nf = 0; nf < 4; ++nf)
        acc[mf][nf] = __builtin_amdgcn_mfma_f32_16x16x32_bf16(
            af[mf], bfr[nf], acc[mf][nf], 0, 0, 0);
    cur ^= 1;
  }

  __syncthreads();
  bf16* OT = (bf16*)smem; // [128][132] padded
  const int jrow0 = (lane >> 4) << 2;
  const int b = m0 >> 10, t0 = m0 & 1023;
  if (ybl < 8) { // Q or K: stage row-major (row=m, col=n)
#pragma unroll
    for (int nf = 0; nf < 4; ++nf) {
      const float bv = bias[n0 + wc * 64 + nf * 16 + ml];
#pragma unroll
      for (int mf = 0; mf < 4; ++mf)
#pragma unroll
        for (int j = 0; j < 4; ++j)
          OT[(wr * 64 + mf * 16 + jrow0 + j) * 132 + wc * 64 + nf * 16 + ml] =
              (bf16)(acc[mf][nf][j] + bv);
    }
    __syncthreads();
    bf16* dst = isq ? q_buf : k_buf;
    const int h0 = n0 >> 6;
#pragma unroll
    for (int it = 0; it < 8; ++it) {
      const int idx = it * 256 + tid;
      const int dg = idx & 7, r = (idx >> 3) & 127, hl = idx >> 10;
      *(bf16x8*)&dst[(((size_t)b * 8 + h0 + hl) * 1024 + t0 + r) * 64 + dg * 8] =
          *(const bf16x8*)&OT[r * 132 + hl * 64 + dg * 8];
    }
  } else { // V: stage col-major for t-contiguous stores
#pragma unroll
    for (int nf = 0; nf < 4; ++nf) {
      const float bv = bias[n0 + wc * 64 + nf * 16 + ml];
#pragma unroll
      for (int mf = 0; mf < 4; ++mf) {
        bf16x4 o;
#pragma unroll
        for (int j = 0; j < 4; ++j) o[j] = (bf16)(acc[mf][nf][j] + bv);
        *(bf16x4*)&OT[(wc * 64 + nf * 16 + ml) * 132 + wr * 64 + mf * 16 + jrow0] = o;
      }
    }
    __syncthreads();
    const int h0 = (n0 - 512) >> 6;
#pragma unroll
    for (int it = 0; it < 8; ++it) {
      const int idx = it * 256 + tid;
      const int og = idx & 15, c = idx >> 4;
      const int hl = c >> 6, d = c & 63;
      *(bf16x8*)&v_t[(((size_t)b * 8 + h0 + hl) * 64 + d) * 1024 + t0 + og * 8] =
          *(const bf16x8*)&OT[c * 132 + og * 8];
    }
  }
}

// ---------------------------------------------------------------------------
// Kernel 5: block-causal flash attention, QBLK=128 (8 waves, 512 threads).
// Grid 512 = (bh-group x qt); XCD-swizzled; qt descending (long first).
// K/V tiles 64 tokens, staged with ONE gload_lds16/thread/matrix; XOR swizzle.
// ---------------------------------------------------------------------------
__global__ __launch_bounds__(512)
void attn_k(const bf16* __restrict__ qb, const bf16* __restrict__ kb,
            const bf16* __restrict__ vt, bf16* __restrict__ y)
{
  __shared__ bf16 Ks[2][4096];
  __shared__ bf16 Vs[2][4096];
  __shared__ bf16 Ps[8][1024];
  const int tid = threadIdx.x, wid = tid >> 6, lane = tid & 63;
  const int L = blockIdx.x;                  // 0..511
  const int xcd = L & 7, chunk = L >> 3;     // chunk 0..63
  const int bh = xcd + ((chunk >> 3) << 3);  // all qt of bh-group on one XCD
  const int qt = 7 - (chunk & 7);            // long blocks first
  const int b = bh >> 3, h = bh & 7;
  const int t0 = qt << 7;
  const int ml = lane & 15, hi = lane >> 4, kg = hi << 3;

  const bf16* qrow = qb + ((size_t)bh * 1024 + t0 + wid * 16) * 64;
  bf16x8 aq[2];
  aq[0] = *(const bf16x8*)&qrow[ml * 64 + kg];
  aq[1] = *(const bf16x8*)&qrow[ml * 64 + 32 + kg];

  f32x4 accO[4] = {};
  float lsum[4] = {0.f, 0.f, 0.f, 0.f};

  const int nkt = ((qt >> 1) + 1) << 2;      // 4..16 tiles of 64 tokens
  const bf16* kbase = kb + (size_t)bh * 1024 * 64;
  const bf16* vbase = vt + (size_t)bh * 64 * 1024;

  // staging: thread covers tile elements tid*8..tid*8+7 -> row sr, granule
  const int sr = tid >> 3;                       // 0..63
  const int sg = ((tid & 7) ^ (sr & 7)) << 3;    // swizzled granule (elems)
  bf16* pw = &Ps[wid][0];

  gload_lds16(kbase + (size_t)sr * 64 + sg,   &Ks[0][wid * 512]);
  gload_lds16(vbase + (size_t)sr * 1024 + sg, &Vs[0][wid * 512]);

  int cur = 0;
  for (int kt = 0; kt < nkt; ++kt) {
    __syncthreads();
    if (kt + 1 < nkt) {
      const int tk0 = (kt + 1) << 6;
      const int nb = cur ^ 1;
      gload_lds16(kbase + (size_t)(tk0 + sr) * 64 + sg,   &Ks[nb][wid * 512]);
      gload_lds16(vbase + (size_t)sr * 1024 + tk0 + sg,   &Vs[nb][wid * 512]);
    }

    f32x4 sa[4] = {};
    __builtin_amdgcn_s_setprio(1);
#pragma unroll
    for (int nf = 0; nf < 4; ++nf) {
      const int row = nf * 16 + ml;
#pragma unroll
      for (int ks = 0; ks < 2; ++ks) {
        const int g = ((ks * 4 + hi) ^ (ml & 7)) << 3;
        bf16x8 bk = *(const bf16x8*)&Ks[cur][row * 64 + g];
        sa[nf] = __builtin_amdgcn_mfma_f32_16x16x32_bf16(aq[ks], bk, sa[nf], 0, 0, 0);
      }
    }
    __builtin_amdgcn_s_setprio(0);

#pragma unroll
    for (int nf = 0; nf < 4; ++nf) {
      const int gp0 = nf * 2 + (ml >> 3);
#pragma unroll
      for (int j = 0; j < 4; ++j) {
        const float p = __expf(sa[nf][j] * 0.125f);
        lsum[j] += p;
        const int prow = (hi << 2) + j;
        pw[prow * 64 + ((gp0 ^ (prow & 7)) << 3) + (ml & 7)] = (bf16)p;
      }
    }

    __builtin_amdgcn_s_setprio(1);
#pragma unroll
    for (int ks = 0; ks < 2; ++ks) {
      const int g = ((ks * 4 + hi) ^ (ml & 7)) << 3;
      bf16x8 pa = *(const bf16x8*)&pw[ml * 64 + g];
#pragma unroll
      for (int df = 0; df < 4; ++df) {
        bf16x8 bv = *(const bf16x8*)&Vs[cur][(df * 16 + ml) * 64 + g];
        accO[df] = __builtin_amdgcn_mfma_f32_16x16x32_bf16(pa, bv, accO[df], 0, 0, 0);
      }
    }
    __builtin_amdgcn_s_setprio(0);
    cur ^= 1;
  }

  float inv[4];
#pragma unroll
  for (int j = 0; j < 4; ++j) {
    float s = lsum[j];
#pragma unroll
    for (int off = 1; off < 16; off <<= 1) s += __shfl_xor(s, off);
    inv[j] = 1.f / s;
  }
#pragma unroll
  for (int df = 0; df < 4; ++df)
#pragma unroll
    for (int j = 0; j < 4; ++j) {
      const int t = t0 + wid * 16 + (hi << 2) + j;
      const int c = h * 64 + df * 16 + ml;
      y[((size_t)b * 1024 + t) * 512 + c] = (bf16)(accO[df][j] * inv[j]);
    }
}

// ---------------------------------------------------------------------------
extern "C" void kernel_launch(void* const* d_in, const int* in_sizes, int n_in,
                              void* d_out, int out_size, void* d_ws, size_t ws_size,
                              hipStream_t stream)
{
  const float* xi    = (const float*)d_in[0];
  const float* xc    = (const float*)d_in[1];
  const float* xj    = (const float*)d_in[2];
  const float* ln1_g = (const float*)d_in[3];
  const float* ln1_b = (const float*)d_in[4];
  const float* ln2_g = (const float*)d_in[5];
  const float* ln2_b = (const float*)d_in[6];
  const float* Wq    = (const float*)d_in[7];
  const float* bq    = (const float*)d_in[8];
  const float* Wkv   = (const float*)d_in[9];
  const float* bkv   = (const float*)d_in[10];
  const float* Wo    = (const float*)d_in[11];
  const float* bo    = (const float*)d_in[12];
  const float* Wfc   = (const float*)d_in[13];
  const float* bfc   = (const float*)d_in[14];
  const float* Wpr   = (const float*)d_in[15];
  const float* bpr   = (const float*)d_in[16];

  char* ws = (char*)d_ws;
  const size_t MB = 1ull << 20;
  bf16*  qs    = (bf16*)(ws + 0);                  // 8 MB
  bf16*  kvs   = (bf16*)(ws + 8 * MB);             // 8 MB
  bf16*  csb   = (bf16*)(ws + 16 * MB);            // 8 MB (bf16 residual)
  bf16*  WqT   = (bf16*)(ws + 32 * MB);
  bf16*  WkvT  = (bf16*)(ws + 32 * MB + 512 * 1024);
  bf16*  WoT   = (bf16*)(ws + 33 * MB + 512 * 1024);
  bf16*  WfcT  = (bf16*)(ws + 34 * MB);
  bf16*  WprT  = (bf16*)(ws + 36 * MB);
  bf16*  q_buf = (bf16*)(ws + 38 * MB);
  bf16*  k_buf = (bf16*)(ws + 46 * MB);
  bf16*  v_t   = (bf16*)(ws + 54 * MB);
  bf16*  yb    = (bf16*)(ws + 0);                  // reuse qs
  bf16*  hcs   = (bf16*)(ws + 8 * MB);             // reuse kvs
  bf16*  fcact = (bf16*)(ws + 38 * MB);            // reuse q/k/v

  prep_k<<<dim3(1536), 256, 0, stream>>>(Wq, Wkv, Wo, Wfc, Wpr,
                                         WqT, WkvT, WoT, WfcT, WprT,
                                         xi, xj, xc, ln1_g, ln1_b, qs, kvs, csb);

  gemm_qkv_k<<<dim3(64, 12), 256, 0, stream>>>(qs, kvs, WqT, WkvT, bq, bkv,
                                               q_buf, k_buf, v_t);

  attn_k<<<dim3(512), 512, 0, stream>>>(q_buf, k_buf, v_t, yb);

  gemmsk_k<EPI_O><<<dim3(128, 4), 512, 0, stream>>>(yb, WoT, bo, csb,
                                                    (void*)csb, 512);

  ln2_k<<<dim3(2048), 256, 0, stream>>>(csb, ln2_g, ln2_b, hcs);

  gemm_fc_k<<<dim3(64, 16), 256, 0, stream>>>(hcs, WfcT, bfc, fcact);

  gemmsk_k<EPI_PR><<<dim3(128, 4), 512, 0, stream>>>(fcact, WprT, bpr, csb,
                                                     d_out, 2048);

  (void)in_sizes; (void)n_in; (void)out_size; (void)ws_size;
}

// Round 13
// 153.112 us; speedup vs baseline: 1.1930x; 1.0138x over previous
//
#include <hip/hip_runtime.h>
#include <hip/hip_bf16.h>
#include <math.h>

// ---------------------------------------------------------------------------
// CrossCausalAttentionBlock on MI355X (gfx950)
// B=8, T=1024 (V=4 blocks of 256), C=512, NH=8, hd=64
// R13: FC GEMM 128x256 tile / 8 waves (32 MFMA/barrier/wave, 2 blocks/CU);
//      T1 XCD-aware block remap on FC/qkv/O/PR (A-panels L2-local per XCD).
// ---------------------------------------------------------------------------

typedef __bf16 bf16;
typedef __bf16 bf16x8 __attribute__((ext_vector_type(8)));
typedef __bf16 bf16x4 __attribute__((ext_vector_type(4)));
typedef float  f32x4  __attribute__((ext_vector_type(4)));

__device__ __forceinline__ void gload_lds16(const void* g, void* l) {
  __builtin_amdgcn_global_load_lds(
      (__attribute__((address_space(1))) void*)(g),
      (__attribute__((address_space(3))) void*)(l), 16, 0, 0);
}

// ---------------------------------------------------------------------------
// Kernel 1: prep. Blocks 0..767: weight convert 64x64 tiles. 768..1535:
// gather+LN1 h-pair blocks (register-resident, vector loads/stores).
// ---------------------------------------------------------------------------
__global__ __launch_bounds__(256)
void prep_k(const float* __restrict__ Wq, const float* __restrict__ Wkv,
            const float* __restrict__ Wo, const float* __restrict__ Wfc,
            const float* __restrict__ Wpr,
            bf16* __restrict__ WqT, bf16* __restrict__ WkvT,
            bf16* __restrict__ WoT, bf16* __restrict__ WfcT,
            bf16* __restrict__ WprT,
            const float* __restrict__ xi, const float* __restrict__ xj,
            const float* __restrict__ xc,
            const float* __restrict__ g, const float* __restrict__ bb,
            bf16* __restrict__ qs, bf16* __restrict__ kvs,
            bf16* __restrict__ csb)
{
  __shared__ float tile[64 * 65]; // 16.6 KB (wconv half)
  __shared__ float red[4][64];    // 1 KB (LN half)
  const int t = blockIdx.x;
  const int tid = threadIdx.x;
  if (t < 768) { // ---- weight transpose-convert, 64x64 tiles
    const float* W; bf16* Wt; int K, N, nx, tl;
    if (t < 64)        { W = Wq;  Wt = WqT;  K = 512;  N = 512;  nx = 8;  tl = t; }
    else if (t < 192)  { W = Wkv; Wt = WkvT; K = 512;  N = 1024; nx = 16; tl = t - 64; }
    else if (t < 256)  { W = Wo;  Wt = WoT;  K = 512;  N = 512;  nx = 8;  tl = t - 192; }
    else if (t < 512)  { W = Wfc; Wt = WfcT; K = 512;  N = 2048; nx = 32; tl = t - 256; }
    else               { W = Wpr; Wt = WprT; K = 2048; N = 512;  nx = 8;  tl = t - 512; }
    const int bx = tl % nx, by = tl / nx;
    const int n0 = bx << 6, k0 = by << 6;
    const int xl = tid & 15, yl = tid >> 4;
#pragma unroll
    for (int r = 0; r < 4; ++r) {
      const int row = yl + r * 16;
      const f32x4 vv = *(const f32x4*)&W[(size_t)(k0 + row) * N + n0 + xl * 4];
#pragma unroll
      for (int e = 0; e < 4; ++e)
        tile[row * 65 + xl * 4 + e] = vv[e];
    }
    __syncthreads();
    const int xk = tid & 7, nl = tid >> 3;
#pragma unroll
    for (int r2 = 0; r2 < 2; ++r2) {
      const int n = nl + r2 * 32;
      bf16x8 o;
#pragma unroll
      for (int e = 0; e < 8; ++e)
        o[e] = (bf16)tile[(xk * 8 + e) * 65 + n];
      *(bf16x8*)&Wt[(size_t)(n0 + n) * K + k0 + xk * 8] = o;
    }
    return;
  }
  // ---- gather [v,b,c,h,w] -> [b,t,c] + LN1
  const int u = t - 768;
  const int sel = u >> 8, bid = u & 255;
  const int hp = bid & 7, b = (bid >> 3) & 7, v = bid >> 6;
  const float* src = (sel == 0) ? xi : ((sel == 1) ? xj : xc);
  const size_t base = ((size_t)(v * 8 + b) * 512) * 256 + hp * 32;
  const int q8 = tid & 7, chb = tid >> 3;
  const int wid = tid >> 6, lc = (tid >> 3) & 7;
  const int cb = chb << 4;

  float gr[16], br[16];
#pragma unroll
  for (int p = 0; p < 4; ++p) {
    *(f32x4*)&gr[p * 4] = *(const f32x4*)&g[cb + p * 4];
    *(f32x4*)&br[p * 4] = *(const f32x4*)&bb[cb + p * 4];
  }
  f32x4 x[16];
#pragma unroll
  for (int k = 0; k < 16; ++k)
    x[k] = *(const f32x4*)&src[base + (size_t)(cb + k) * 256 + q8 * 4];

  float s[4] = {0.f, 0.f, 0.f, 0.f}, ss[4] = {0.f, 0.f, 0.f, 0.f};
#pragma unroll
  for (int k = 0; k < 16; ++k)
#pragma unroll
    for (int i = 0; i < 4; ++i) {
      s[i] += x[k][i];
      ss[i] += x[k][i] * x[k][i];
    }
#pragma unroll
  for (int off = 8; off < 64; off <<= 1)
#pragma unroll
    for (int i = 0; i < 4; ++i) {
      s[i] += __shfl_xor(s[i], off);
      ss[i] += __shfl_xor(ss[i], off);
    }
  if (lc < 4)      red[wid][q8 * 4 + lc]            = s[lc];
  else             red[wid][32 + q8 * 4 + (lc - 4)] = ss[lc - 4];
  __syncthreads();
  f32x4 st = {0.f, 0.f, 0.f, 0.f}, sst = {0.f, 0.f, 0.f, 0.f};
#pragma unroll
  for (int w = 0; w < 4; ++w) {
    st  += *(const f32x4*)&red[w][q8 * 4];
    sst += *(const f32x4*)&red[w][32 + q8 * 4];
  }
  float mu[4], rs[4];
#pragma unroll
  for (int i = 0; i < 4; ++i) {
    mu[i] = st[i] * (1.f / 512.f);
    rs[i] = rsqrtf(sst[i] * (1.f / 512.f) - mu[i] * mu[i] + 1e-5f);
  }
  bf16* dstb = (sel == 0) ? qs : ((sel == 1) ? kvs : csb);
  const int tkb = v * 256 + hp * 32 + q8 * 4;
#pragma unroll
  for (int i = 0; i < 4; ++i) {
    const size_t orow = ((size_t)b * 1024 + tkb + i) * 512 + cb;
    bf16x8 o0, o1;
#pragma unroll
    for (int k = 0; k < 8; ++k) {
      o0[k] = (bf16)((x[k][i] - mu[i]) * rs[i] * gr[k] + br[k]);
      o1[k] = (bf16)((x[k + 8][i] - mu[i]) * rs[i] * gr[k + 8] + br[k + 8]);
    }
    *(bf16x8*)&dstb[orow]     = o0;
    *(bf16x8*)&dstb[orow + 8] = o1;
  }
}

// ---------------------------------------------------------------------------
// Kernel 3: row LayerNorm(ln2) on cs bf16[8192][512] -> hcs bf16. 1 wave/row.
// ---------------------------------------------------------------------------
__global__ __launch_bounds__(256)
void ln2_k(const bf16* __restrict__ cs, const float* __restrict__ g,
           const float* __restrict__ bb, bf16* __restrict__ hcs)
{
  const int tid = threadIdx.x, wid = tid >> 6, lane = tid & 63;
  const int row = blockIdx.x * 4 + wid;
  const bf16x8 v8 = *(const bf16x8*)&cs[(size_t)row * 512 + lane * 8];
  float v[8];
#pragma unroll
  for (int k = 0; k < 8; ++k) v[k] = (float)v8[k];
  float s = 0.f, ss = 0.f;
#pragma unroll
  for (int k = 0; k < 8; ++k) { s += v[k]; ss += v[k] * v[k]; }
#pragma unroll
  for (int off = 1; off < 64; off <<= 1) {
    s += __shfl_xor(s, off);
    ss += __shfl_xor(ss, off);
  }
  const float mu = s * (1.f / 512.f);
  const float rstd = rsqrtf(ss * (1.f / 512.f) - mu * mu + 1e-5f);
  bf16x8 o;
#pragma unroll
  for (int k = 0; k < 8; ++k) {
    int ch = lane * 8 + k;
    o[k] = (bf16)((v[k] - mu) * rstd * g[ch] + bb[ch]);
  }
  *(bf16x8*)&hcs[(size_t)row * 512 + lane * 8] = o;
}

// ---------------------------------------------------------------------------
// Kernel 4: FC GEMM (M=8192, N=2048, K=512). 128x256 tile, 8 waves (2x4),
// 2-phase dbuf, GELU epilogue staged via padded LDS. Grid 512 (1D),
// XCD-remapped: xcd = bid&7 owns an m-chunk (A slice L2-local).
// ---------------------------------------------------------------------------
__global__ __launch_bounds__(512)
void gemm_fc_k(const bf16* __restrict__ A, const bf16* __restrict__ Bt,
               const float* __restrict__ bias, bf16* __restrict__ fo)
{
  const int K = 512;
  __shared__ __align__(16) char smem[69632]; // 68 KB
  bf16* As = (bf16*)smem;            // [2][4096] = 16 KB
  bf16* Bs = (bf16*)(smem + 16384);  // [2][8192] = 32 KB
  bf16* OT = (bf16*)smem;            // [128][264] = 67.6 KB (epilogue overlay)
  const int tid = threadIdx.x;
  const int wid = tid >> 6, lane = tid & 63;
  const int wr = wid >> 2, wcc = wid & 3;
  const int ml = lane & 15, kg = (lane >> 4) << 3;
  // XCD remap: 8 xcd x 8 m-sub x 8 n  (64 m-blocks x 8 n-blocks)
  const int bid = blockIdx.x;
  const int xcd = bid & 7, chunk = bid >> 3;
  const int m0 = (xcd * 8 + (chunk & 7)) * 128;
  const int n0 = (chunk >> 3) * 256;

  // staging decode: elem = wid*512 + lane*8
  const int rA = (wid << 4) + (lane >> 2), cA = (lane & 3) << 3;
  const bf16* Ag = A + (size_t)m0 * K;
  const bf16* Bg = Bt + (size_t)n0 * K;

  f32x4 acc[4][4] = {};

  gload_lds16(Ag + (size_t)rA * K + cA,         As + wid * 512);
  gload_lds16(Bg + (size_t)rA * K + cA,         Bs + wid * 512);
  gload_lds16(Bg + (size_t)(rA + 128) * K + cA, Bs + 4096 + wid * 512);

  int cur = 0;
  for (int k0 = 0; k0 < K; k0 += 32) {
    __syncthreads();
    if (k0 + 32 < K) {
      const int nb = cur ^ 1, kn = k0 + 32;
      gload_lds16(Ag + (size_t)rA * K + kn + cA,         As + nb * 4096 + wid * 512);
      gload_lds16(Bg + (size_t)rA * K + kn + cA,         Bs + nb * 8192 + wid * 512);
      gload_lds16(Bg + (size_t)(rA + 128) * K + kn + cA, Bs + nb * 8192 + 4096 + wid * 512);
    }
    bf16x8 af[4], bfr[4];
#pragma unroll
    for (int mf = 0; mf < 4; ++mf)
      af[mf] = *(const bf16x8*)&As[cur * 4096 + (wr * 64 + mf * 16 + ml) * 32 + kg];
#pragma unroll
    for (int nf = 0; nf < 4; ++nf)
      bfr[nf] = *(const bf16x8*)&Bs[cur * 8192 + (wcc * 64 + nf * 16 + ml) * 32 + kg];
#pragma unroll
    for (int mf = 0; mf < 4; ++mf)
#pragma unroll
      for (int nf = 0; nf < 4; ++nf)
        acc[mf][nf] = __builtin_amdgcn_mfma_f32_16x16x32_bf16(
            af[mf], bfr[nf], acc[mf][nf], 0, 0, 0);
    cur ^= 1;
  }

  __syncthreads();
  const int jrow0 = (lane >> 4) << 2;
#pragma unroll
  for (int nf = 0; nf < 4; ++nf) {
    const float bv = bias[n0 + wcc * 64 + nf * 16 + ml];
#pragma unroll
    for (int mf = 0; mf < 4; ++mf)
#pragma unroll
      for (int j = 0; j < 4; ++j) {
        float x = acc[mf][nf][j] + bv;
        float u = 0.7978845608f * (x + 0.044715f * x * x * x);
        float e = __expf(2.f * u);
        float th = 1.f - 2.f / (e + 1.f);
        OT[(wr * 64 + mf * 16 + jrow0 + j) * 264 + wcc * 64 + nf * 16 + ml] =
            (bf16)(0.5f * x * (1.f + th));
      }
  }
  __syncthreads();
#pragma unroll
  for (int it = 0; it < 8; ++it) {
    const int idx = it * 512 + tid;
    const int cg = idx & 31, r = idx >> 5;
    *(bf16x8*)&fo[(size_t)(m0 + r) * 2048 + n0 + cg * 8] =
        *(const bf16x8*)&OT[r * 264 + cg * 8];
  }
}

// ---------------------------------------------------------------------------
// Kernel 4b: in-block split-K GEMM for N=512 stages (O, PR). BM=64, BN=128,
// grid 512 (1D, XCD-remapped: 8 xcd x 16 m-sub x 4 n). 2 K-half groups.
// ---------------------------------------------------------------------------
enum { EPI_O = 2, EPI_PR = 4 };

template <int EPI>
__global__ __launch_bounds__(512)
void gemmsk_k(const bf16* __restrict__ A, const bf16* __restrict__ Bt,
              const float* __restrict__ bias, const bf16* res,
              void* out0, int K)
{
  __shared__ __align__(16) char smem[49152];
  bf16*  AS = (bf16*)smem;            // [2 dbuf][2 half][2048] = 16 KB
  bf16*  BS = (bf16*)(smem + 16384);  // [2 dbuf][2 half][4096] = 32 KB
  float* CF = (float*)smem;           // f32[64][128] = 32 KB overlay

  const int tid = threadIdx.x;
  const int wid = tid >> 6, lane = tid & 63;
  const int half = wid >> 2, w2 = wid & 3;
  const int wr = w2 >> 1, wc = w2 & 1;
  const int ml = lane & 15, kg = (lane >> 4) << 3;
  // XCD remap: 8 xcd x 16 m-sub x 4 n  (128 m-blocks x 4 n-blocks)
  const int bid = blockIdx.x;
  const int xcd = bid & 7, chunk = bid >> 3;
  const int m0 = (xcd * 16 + (chunk & 15)) * 64;
  const int n0 = (chunk >> 4) * 128;
  const int Kh = K >> 1;

  const int eA = w2 * 512 + lane * 8;
  const int rA = eA >> 5, cA = eA & 31;
  const int eB0 = (w2 * 2) * 512 + lane * 8;
  const int rB0 = eB0 >> 5, cB0 = eB0 & 31;
  const int eB1 = eB0 + 512;
  const int rB1 = eB1 >> 5, cB1 = eB1 & 31;

  const bf16* Ag = A + (size_t)m0 * K + half * Kh;
  const bf16* Bg = Bt + (size_t)n0 * K + half * Kh;

  f32x4 acc[2][4] = {};

  gload_lds16(Ag + (size_t)rA * K + cA, AS + half * 2048 + w2 * 512);
  gload_lds16(Bg + (size_t)rB0 * K + cB0, BS + half * 4096 + (w2 * 2) * 512);
  gload_lds16(Bg + (size_t)rB1 * K + cB1, BS + half * 4096 + (w2 * 2 + 1) * 512);

  int cur = 0;
  for (int k0 = 0; k0 < Kh; k0 += 32) {
    __syncthreads();
    if (k0 + 32 < Kh) {
      const int kn = k0 + 32, nb = cur ^ 1;
      gload_lds16(Ag + (size_t)rA * K + kn + cA,
                  AS + nb * 4096 + half * 2048 + w2 * 512);
      gload_lds16(Bg + (size_t)rB0 * K + kn + cB0,
                  BS + nb * 8192 + half * 4096 + (w2 * 2) * 512);
      gload_lds16(Bg + (size_t)rB1 * K + kn + cB1,
                  BS + nb * 8192 + half * 4096 + (w2 * 2 + 1) * 512);
    }
    const bf16* Ac = AS + cur * 4096 + half * 2048;
    const bf16* Bc = BS + cur * 8192 + half * 4096;
    bf16x8 af[2], bfr[4];
#pragma unroll
    for (int mf = 0; mf < 2; ++mf)
      af[mf] = *(const bf16x8*)&Ac[(wr * 32 + mf * 16 + ml) * 32 + kg];
#pragma unroll
    for (int nf = 0; nf < 4; ++nf)
      bfr[nf] = *(const bf16x8*)&Bc[(wc * 64 + nf * 16 + ml) * 32 + kg];
#pragma unroll
    for (int mf = 0; mf < 2; ++mf)
#pragma unroll
      for (int nf = 0; nf < 4; ++nf)
        acc[mf][nf] = __builtin_amdgcn_mfma_f32_16x16x32_bf16(
            af[mf], bfr[nf], acc[mf][nf], 0, 0, 0);
    cur ^= 1;
  }

  const int jrow0 = (lane >> 4) << 2;
  __syncthreads(); // staging dead; CF may overlay AS/BS
  if (half == 0) {
#pragma unroll
    for (int mf = 0; mf < 2; ++mf)
#pragma unroll
      for (int nf = 0; nf < 4; ++nf)
#pragma unroll
        for (int j = 0; j < 4; ++j)
          CF[(wr * 32 + mf * 16 + jrow0 + j) * 128 + wc * 64 + nf * 16 + ml] =
              acc[mf][nf][j];
  }
  __syncthreads();
  if (half == 1) {
#pragma unroll
    for (int nf = 0; nf < 4; ++nf) {
      const int n = n0 + wc * 64 + nf * 16 + ml;
      const float bv = bias[n];
#pragma unroll
      for (int mf = 0; mf < 2; ++mf) {
        const int mbase = m0 + wr * 32 + mf * 16 + jrow0;
        float v4[4];
#pragma unroll
        for (int j = 0; j < 4; ++j)
          v4[j] = acc[mf][nf][j] +
                  CF[(wr * 32 + mf * 16 + jrow0 + j) * 128 + wc * 64 + nf * 16 + ml];
        if constexpr (EPI == EPI_O) {
          bf16* cs = (bf16*)out0; // in-place with res
#pragma unroll
          for (int j = 0; j < 4; ++j) {
            const size_t idx = (size_t)(mbase + j) * 512 + n;
            cs[idx] = (bf16)(v4[j] + bv + (float)res[idx]);
          }
        } else {
          float* out = (float*)out0;
          const int b = mbase >> 10, t = mbase & 1023;
          const int v = t >> 8, hhh = (t >> 4) & 15, w0 = t & 15;
          f32x4 o;
#pragma unroll
          for (int j = 0; j < 4; ++j)
            o[j] = v4[j] + bv + (float)res[(size_t)(mbase + j) * 512 + n];
          *(f32x4*)&out[(((size_t)v * 8 + b) * 512 + n) * 256 + hhh * 16 + w0] = o;
        }
      }
    }
  }
}

// ---------------------------------------------------------------------------
// Kernel 4c: merged Q + KV projection GEMM, 2-phase dbuf, LDS-staged stores.
// Grid 768 (1D, XCD-remapped: 8 xcd x 8 m-sub x 12 ybl).
// ---------------------------------------------------------------------------
__global__ __launch_bounds__(256)
void gemm_qkv_k(const bf16* __restrict__ Aq, const bf16* __restrict__ Akv,
                const bf16* __restrict__ WqT, const bf16* __restrict__ WkvT,
                const float* __restrict__ bq, const float* __restrict__ bkv,
                bf16* __restrict__ q_buf, bf16* __restrict__ k_buf,
                bf16* __restrict__ v_t)
{
  const int K = 512;
  __shared__ __align__(16) char smem[34816];
  bf16* As = (bf16*)smem;
  bf16* Bs = (bf16*)(smem + 16384);
  const int tid = threadIdx.x;
  const int wid = tid >> 6, lane = tid & 63;
  const int wr = wid >> 1, wc = wid & 1;
  const int ml = lane & 15, kg = (lane >> 4) << 3;
  // XCD remap: 8 xcd x 8 m-sub x 12 ybl
  const int bid = blockIdx.x;
  const int xcd = bid & 7, chunk = bid >> 3;
  const int m0 = (xcd * 8 + (chunk & 7)) * 128;
  const int ybl = chunk >> 3;
  const bool isq = ybl < 4;
  const bf16* A     = isq ? Aq  : Akv;
  const bf16* Bt    = isq ? WqT : WkvT;
  const float* bias = isq ? bq : bkv;
  const int n0 = isq ? (ybl << 7) : ((ybl - 4) << 7);

  const int e0 = wid * 512 + lane * 8;
  const int r0 = e0 >> 5, c0 = e0 & 31;
  const int e1 = e0 + 2048;
  const int r1 = e1 >> 5, c1 = e1 & 31;

  const bf16* Ag = A + (size_t)m0 * K;
  const bf16* Bg = Bt + (size_t)n0 * K;

  f32x4 acc[4][4] = {};

  gload_lds16(Ag + (size_t)r0 * K + c0, As + wid * 512);
  gload_lds16(Ag + (size_t)r1 * K + c1, As + 2048 + wid * 512);
  gload_lds16(Bg + (size_t)r0 * K + c0, Bs + wid * 512);
  gload_lds16(Bg + (size_t)r1 * K + c1, Bs + 2048 + wid * 512);

  int cur = 0;
  for (int k0 = 0; k0 < K; k0 += 32) {
    __syncthreads();
    if (k0 + 32 < K) {
      const int nb = cur ^ 1, kn = k0 + 32;
      gload_lds16(Ag + (size_t)r0 * K + kn + c0, As + nb * 4096 + wid * 512);
      gload_lds16(Ag + (size_t)r1 * K + kn + c1, As + nb * 4096 + 2048 + wid * 512);
      gload_lds16(Bg + (size_t)r0 * K + kn + c0, Bs + nb * 4096 + wid * 512);
      gload_lds16(Bg + (size_t)r1 * K + kn + c1, Bs + nb * 4096 + 2048 + wid * 512);
    }
    bf16x8 af[4], bfr[4];
#pragma unroll
    for (int mf = 0; mf < 4; ++mf)
      af[mf] = *(const bf16x8*)&As[cur * 4096 + (wr * 64 + mf * 16 + ml) * 32 + kg];
#pragma unroll
    for (int nf = 0; nf < 4; ++nf)
      bfr[nf] = *(const bf16x8*)&Bs[cur * 4096 + (wc * 64 + nf * 16 + ml) * 32 + kg];
#pragma unroll
    for (int mf = 0; mf < 4; ++mf)
#pragma unroll
      for (int nf = 0; nf < 4; ++nf)
        acc[mf][nf] = __builtin_amdgcn_mfma_f32_16x16x32_bf16(
            af[mf], bfr[nf], acc[mf][nf], 0, 0, 0);
    cur ^= 1;
  }

  __syncthreads();
  bf16* OT = (bf16*)smem; // [128][132] padded
  const int jrow0 = (lane >> 4) << 2;
  const int b = m0 >> 10, t0 = m0 & 1023;
  if (ybl < 8) { // Q or K: stage row-major (row=m, col=n)
#pragma unroll
    for (int nf = 0; nf < 4; ++nf) {
      const float bv = bias[n0 + wc * 64 + nf * 16 + ml];
#pragma unroll
      for (int mf = 0; mf < 4; ++mf)
#pragma unroll
        for (int j = 0; j < 4; ++j)
          OT[(wr * 64 + mf * 16 + jrow0 + j) * 132 + wc * 64 + nf * 16 + ml] =
              (bf16)(acc[mf][nf][j] + bv);
    }
    __syncthreads();
    bf16* dst = isq ? q_buf : k_buf;
    const int h0 = n0 >> 6;
#pragma unroll
    for (int it = 0; it < 8; ++it) {
      const int idx = it * 256 + tid;
      const int dg = idx & 7, r = (idx >> 3) & 127, hl = idx >> 10;
      *(bf16x8*)&dst[(((size_t)b * 8 + h0 + hl) * 1024 + t0 + r) * 64 + dg * 8] =
          *(const bf16x8*)&OT[r * 132 + hl * 64 + dg * 8];
    }
  } else { // V: stage col-major for t-contiguous stores
#pragma unroll
    for (int nf = 0; nf < 4; ++nf) {
      const float bv = bias[n0 + wc * 64 + nf * 16 + ml];
#pragma unroll
      for (int mf = 0; mf < 4; ++mf) {
        bf16x4 o;
#pragma unroll
        for (int j = 0; j < 4; ++j) o[j] = (bf16)(acc[mf][nf][j] + bv);
        *(bf16x4*)&OT[(wc * 64 + nf * 16 + ml) * 132 + wr * 64 + mf * 16 + jrow0] = o;
      }
    }
    __syncthreads();
    const int h0 = (n0 - 512) >> 6;
#pragma unroll
    for (int it = 0; it < 8; ++it) {
      const int idx = it * 256 + tid;
      const int og = idx & 15, c = idx >> 4;
      const int hl = c >> 6, d = c & 63;
      *(bf16x8*)&v_t[(((size_t)b * 8 + h0 + hl) * 64 + d) * 1024 + t0 + og * 8] =
          *(const bf16x8*)&OT[c * 132 + og * 8];
    }
  }
}

// ---------------------------------------------------------------------------
// Kernel 5: block-causal flash attention, QBLK=128 (8 waves, 512 threads).
// Grid 512 = (bh-group x qt); XCD-swizzled; qt descending (long first).
// ---------------------------------------------------------------------------
__global__ __launch_bounds__(512)
void attn_k(const bf16* __restrict__ qb, const bf16* __restrict__ kb,
            const bf16* __restrict__ vt, bf16* __restrict__ y)
{
  __shared__ bf16 Ks[2][4096];
  __shared__ bf16 Vs[2][4096];
  __shared__ bf16 Ps[8][1024];
  const int tid = threadIdx.x, wid = tid >> 6, lane = tid & 63;
  const int L = blockIdx.x;                  // 0..511
  const int xcd = L & 7, chunk = L >> 3;     // chunk 0..63
  const int bh = xcd + ((chunk >> 3) << 3);  // all qt of bh-group on one XCD
  const int qt = 7 - (chunk & 7);            // long blocks first
  const int b = bh >> 3, h = bh & 7;
  const int t0 = qt << 7;
  const int ml = lane & 15, hi = lane >> 4, kg = hi << 3;

  const bf16* qrow = qb + ((size_t)bh * 1024 + t0 + wid * 16) * 64;
  bf16x8 aq[2];
  aq[0] = *(const bf16x8*)&qrow[ml * 64 + kg];
  aq[1] = *(const bf16x8*)&qrow[ml * 64 + 32 + kg];

  f32x4 accO[4] = {};
  float lsum[4] = {0.f, 0.f, 0.f, 0.f};

  const int nkt = ((qt >> 1) + 1) << 2;      // 4..16 tiles of 64 tokens
  const bf16* kbase = kb + (size_t)bh * 1024 * 64;
  const bf16* vbase = vt + (size_t)bh * 64 * 1024;

  const int sr = tid >> 3;                       // 0..63
  const int sg = ((tid & 7) ^ (sr & 7)) << 3;    // swizzled granule (elems)
  bf16* pw = &Ps[wid][0];

  gload_lds16(kbase + (size_t)sr * 64 + sg,   &Ks[0][wid * 512]);
  gload_lds16(vbase + (size_t)sr * 1024 + sg, &Vs[0][wid * 512]);

  int cur = 0;
  for (int kt = 0; kt < nkt; ++kt) {
    __syncthreads();
    if (kt + 1 < nkt) {
      const int tk0 = (kt + 1) << 6;
      const int nb = cur ^ 1;
      gload_lds16(kbase + (size_t)(tk0 + sr) * 64 + sg,   &Ks[nb][wid * 512]);
      gload_lds16(vbase + (size_t)sr * 1024 + tk0 + sg,   &Vs[nb][wid * 512]);
    }

    f32x4 sa[4] = {};
    __builtin_amdgcn_s_setprio(1);
#pragma unroll
    for (int nf = 0; nf < 4; ++nf) {
      const int row = nf * 16 + ml;
#pragma unroll
      for (int ks = 0; ks < 2; ++ks) {
        const int g = ((ks * 4 + hi) ^ (ml & 7)) << 3;
        bf16x8 bk = *(const bf16x8*)&Ks[cur][row * 64 + g];
        sa[nf] = __builtin_amdgcn_mfma_f32_16x16x32_bf16(aq[ks], bk, sa[nf], 0, 0, 0);
      }
    }
    __builtin_amdgcn_s_setprio(0);

#pragma unroll
    for (int nf = 0; nf < 4; ++nf) {
      const int gp0 = nf * 2 + (ml >> 3);
#pragma unroll
      for (int j = 0; j < 4; ++j) {
        const float p = __expf(sa[nf][j] * 0.125f);
        lsum[j] += p;
        const int prow = (hi << 2) + j;
        pw[prow * 64 + ((gp0 ^ (prow & 7)) << 3) + (ml & 7)] = (bf16)p;
      }
    }

    __builtin_amdgcn_s_setprio(1);
#pragma unroll
    for (int ks = 0; ks < 2; ++ks) {
      const int g = ((ks * 4 + hi) ^ (ml & 7)) << 3;
      bf16x8 pa = *(const bf16x8*)&pw[ml * 64 + g];
#pragma unroll
      for (int df = 0; df < 4; ++df) {
        bf16x8 bv = *(const bf16x8*)&Vs[cur][(df * 16 + ml) * 64 + g];
        accO[df] = __builtin_amdgcn_mfma_f32_16x16x32_bf16(pa, bv, accO[df], 0, 0, 0);
      }
    }
    __builtin_amdgcn_s_setprio(0);
    cur ^= 1;
  }

  float inv[4];
#pragma unroll
  for (int j = 0; j < 4; ++j) {
    float s = lsum[j];
#pragma unroll
    for (int off = 1; off < 16; off <<= 1) s += __shfl_xor(s, off);
    inv[j] = 1.f / s;
  }
#pragma unroll
  for (int df = 0; df < 4; ++df)
#pragma unroll
    for (int j = 0; j < 4; ++j) {
      const int t = t0 + wid * 16 + (hi << 2) + j;
      const int c = h * 64 + df * 16 + ml;
      y[((size_t)b * 1024 + t) * 512 + c] = (bf16)(accO[df][j] * inv[j]);
    }
}

// ---------------------------------------------------------------------------
extern "C" void kernel_launch(void* const* d_in, const int* in_sizes, int n_in,
                              void* d_out, int out_size, void* d_ws, size_t ws_size,
                              hipStream_t stream)
{
  const float* xi    = (const float*)d_in[0];
  const float* xc    = (const float*)d_in[1];
  const float* xj    = (const float*)d_in[2];
  const float* ln1_g = (const float*)d_in[3];
  const float* ln1_b = (const float*)d_in[4];
  const float* ln2_g = (const float*)d_in[5];
  const float* ln2_b = (const float*)d_in[6];
  const float* Wq    = (const float*)d_in[7];
  const float* bq    = (const float*)d_in[8];
  const float* Wkv   = (const float*)d_in[9];
  const float* bkv   = (const float*)d_in[10];
  const float* Wo    = (const float*)d_in[11];
  const float* bo    = (const float*)d_in[12];
  const float* Wfc   = (const float*)d_in[13];
  const float* bfc   = (const float*)d_in[14];
  const float* Wpr   = (const float*)d_in[15];
  const float* bpr   = (const float*)d_in[16];

  char* ws = (char*)d_ws;
  const size_t MB = 1ull << 20;
  bf16*  qs    = (bf16*)(ws + 0);                  // 8 MB
  bf16*  kvs   = (bf16*)(ws + 8 * MB);             // 8 MB
  bf16*  csb   = (bf16*)(ws + 16 * MB);            // 8 MB (bf16 residual)
  bf16*  WqT   = (bf16*)(ws + 32 * MB);
  bf16*  WkvT  = (bf16*)(ws + 32 * MB + 512 * 1024);
  bf16*  WoT   = (bf16*)(ws + 33 * MB + 512 * 1024);
  bf16*  WfcT  = (bf16*)(ws + 34 * MB);
  bf16*  WprT  = (bf16*)(ws + 36 * MB);
  bf16*  q_buf = (bf16*)(ws + 38 * MB);
  bf16*  k_buf = (bf16*)(ws + 46 * MB);
  bf16*  v_t   = (bf16*)(ws + 54 * MB);
  bf16*  yb    = (bf16*)(ws + 0);                  // reuse qs
  bf16*  hcs   = (bf16*)(ws + 8 * MB);             // reuse kvs
  bf16*  fcact = (bf16*)(ws + 38 * MB);            // reuse q/k/v

  prep_k<<<dim3(1536), 256, 0, stream>>>(Wq, Wkv, Wo, Wfc, Wpr,
                                         WqT, WkvT, WoT, WfcT, WprT,
                                         xi, xj, xc, ln1_g, ln1_b, qs, kvs, csb);

  gemm_qkv_k<<<dim3(768), 256, 0, stream>>>(qs, kvs, WqT, WkvT, bq, bkv,
                                            q_buf, k_buf, v_t);

  attn_k<<<dim3(512), 512, 0, stream>>>(q_buf, k_buf, v_t, yb);

  gemmsk_k<EPI_O><<<dim3(512), 512, 0, stream>>>(yb, WoT, bo, csb,
                                                 (void*)csb, 512);

  ln2_k<<<dim3(2048), 256, 0, stream>>>(csb, ln2_g, ln2_b, hcs);

  gemm_fc_k<<<dim3(512), 512, 0, stream>>>(hcs, WfcT, bfc, fcact);

  gemmsk_k<EPI_PR><<<dim3(512), 512, 0, stream>>>(fcact, WprT, bpr, csb,
                                                  d_out, 2048);

  (void)in_sizes; (void)n_in; (void)out_size; (void)ws_size;
}